// Round 9
// baseline (258929.858 us; speedup 1.0000x reference)
//
#include <hip/hip_runtime.h>

#define B_    128
#define A_    4
#define N_    128
#define F_IN_ 16
#define H_    256
#define HEADS_ 4
#define FF_   512
#define OUT_  64
#define BF_   3
#define L_    2
#define T_    512          // B*A
#define E_    127          // N-1
#define DH_   64
#define P_    384          // N*BF
#define TOK_  65536        // T*N

typedef unsigned short u16;

__device__ __forceinline__ float u2f(u16 u) {
    return __uint_as_float(((unsigned)u) << 16);
}
__device__ __forceinline__ u16 f2bf(float f) {
    unsigned u = __float_as_uint(f);
    unsigned r = (u + 0x7fffu + ((u >> 16) & 1u)) >> 16;
    return (u16)r;
}
// flag-selected float read: bf=0 -> fp32 array, bf=1 -> bf16 array
__device__ __forceinline__ float ldf(const void* p, size_t i, int bf) {
    return bf ? u2f(((const u16*)p)[i]) : ((const float*)p)[i];
}

// ---------------------------------------------------------------------------
// dtype probe on resolved ln1_w (all ones):
// fp32 word = 0x3F800000 ; bf16 pair = 0x3F803F80
// ---------------------------------------------------------------------------
__global__ void k_detect(const void* __restrict__ ln1_w, int* __restrict__ flag)
{
    unsigned w = ((const unsigned*)ln1_w)[0];
    *flag = (w == 0x3F800000u) ? 0 : 1;
}

// ---------------------------------------------------------------------------
// Literal transcription of the reference pos_encoding scan.
// One thread per tree; edges in row order (parent row < child row by
// construction, so the parent's mask is final before its children).
// pos[child] = pos[parent] | onehot(parent_depth*3 + slot_idx); entries are
// 0/1 so a 15-bit mask per node suffices (max parent depth 4).
// depth = max(node_order over tree) - node_order, exactly as the reference.
// ---------------------------------------------------------------------------
__global__ __launch_bounds__(256) void k_pos(
        const int* __restrict__ adj, const int* __restrict__ no,
        int* __restrict__ mask)
{
    int t = blockIdx.x * 256 + threadIdx.x;
    if (t >= T_) return;
    const int* noT = no + (size_t)t * N_;
    int mx = noT[0];
    for (int i = 1; i < N_; ++i) mx = max(mx, noT[i]);
    int* mk = mask + (size_t)t * N_;
    mk[0] = 0;
    for (int r = 0; r < E_; ++r) {
        const int* e = adj + ((size_t)t * E_ + r) * 3;
        int pg = e[0], cg = e[1], sl = e[2];
        if (pg < 0 || cg < 0) continue;
        int p = pg - t * N_;
        int c = cg - t * N_;
        if (p < 0 || p >= N_ || c < 0 || c >= N_) continue;
        int sli = sl + 1;
        sli = sli < 0 ? 0 : (sli > BF_ - 1 ? BF_ - 1 : sli);
        int pd = mx - noT[p];
        int bit = pd * BF_ + sli;
        if (bit >= 0 && bit < 31)
            mk[c] = mk[p] | (1 << bit);
        else
            mk[c] = mk[p];
    }
}

// ---------------------------------------------------------------------------
// x0 = forest @ W_in^T + b_in + pos @ W_pos^T + b_pos  -> bf16 x
// grid = TOK_, block = 256 (thread = channel h)
// ---------------------------------------------------------------------------
__global__ __launch_bounds__(256) void k_init_x(
        const void* __restrict__ forest, const int* __restrict__ mask,
        const void* __restrict__ W_in, const void* __restrict__ b_in,
        const void* __restrict__ W_pos, const void* __restrict__ b_pos,
        u16* __restrict__ x, const int* __restrict__ flag)
{
    const int bf = *flag;
    int tn = blockIdx.x;
    int h = threadIdx.x;

    float acc = ldf(b_in, h, bf) + ldf(b_pos, h, bf);
#pragma unroll
    for (int f = 0; f < F_IN_; ++f)
        acc += ldf(forest, (size_t)tn * F_IN_ + f, bf)
             * ldf(W_in, (size_t)h * F_IN_ + f, bf);

    unsigned mk = (unsigned)mask[tn];
#pragma unroll
    for (int bit = 0; bit < 15; ++bit)
        if (mk & (1u << bit))
            acc += ldf(W_pos, (size_t)h * P_ + bit, bf);

    x[(size_t)tn * H_ + h] = f2bf(acc);
}

// ---------------------------------------------------------------------------
// Naive GEMM, one thread per output element:
// C[m*ldc+n] = act( sum_k A[m*lda+k] * Bw[boff+n*ldb+k] + bias[biasoff+n] )
// A bf16 activations; Bw/bias dtype per flag; fp32 accumulate.
// ---------------------------------------------------------------------------
__global__ __launch_bounds__(256) void k_gemm_naive(
        const u16* __restrict__ A, int lda,
        const void* __restrict__ Bw, size_t boff, int ldb,
        const void* __restrict__ bias, size_t biasoff,
        u16* __restrict__ C, int ldc,
        int M, int Nc, int K, int relu, const int* __restrict__ flag)
{
    const int bf = *flag;
    int idx = blockIdx.x * 256 + threadIdx.x;
    if (idx >= M * Nc) return;
    int m = idx / Nc;
    int n = idx - m * Nc;
    const u16* a = A + (size_t)m * lda;
    size_t bbase = boff + (size_t)n * ldb;
    float acc = 0.f;
    for (int k = 0; k < K; ++k)
        acc += u2f(a[k]) * ldf(Bw, bbase + k, bf);
    if (bias) acc += ldf(bias, biasoff + n, bf);
    if (relu) acc = fmaxf(acc, 0.f);
    C[(size_t)m * ldc + n] = f2bf(acc);
}

// ---------------------------------------------------------------------------
// Naive attention: one thread per (token, head). Two-pass softmax.
// Reads own Q slice + the tree's K/V slices, writes ONLY its own Q slice.
// qkv rows: [0..256) Q | [256..512) K | [512..768) V; head hd at +hd*64.
// ---------------------------------------------------------------------------
__global__ __launch_bounds__(256) void k_attn(u16* __restrict__ qkv, int ntok)
{
    int idx = blockIdx.x * 256 + threadIdx.x;
    if (idx >= ntok * HEADS_) return;
    int tok = idx >> 2, hd = idx & 3;
    int tree = tok >> 7;                       // chunk-local tree
    const u16* base = qkv + (size_t)tree * N_ * 768;
    u16* qp = qkv + (size_t)tok * 768 + hd * 64;

    float q[64];
#pragma unroll
    for (int d = 0; d < 64; ++d) q[d] = u2f(qp[d]);

    float mx = -3e38f;
    for (int j = 0; j < N_; ++j) {
        const u16* kr = base + (size_t)j * 768 + 256 + hd * 64;
        float a = 0.f;
#pragma unroll
        for (int d = 0; d < 64; ++d) a += q[d] * u2f(kr[d]);
        mx = fmaxf(mx, a * 0.125f);
    }
    float sum = 0.f, o[64];
#pragma unroll
    for (int d = 0; d < 64; ++d) o[d] = 0.f;
    for (int j = 0; j < N_; ++j) {
        const u16* kr = base + (size_t)j * 768 + 256 + hd * 64;
        float a = 0.f;
#pragma unroll
        for (int d = 0; d < 64; ++d) a += q[d] * u2f(kr[d]);
        float p = __expf(a * 0.125f - mx);
        sum += p;
        const u16* vr = base + (size_t)j * 768 + 512 + hd * 64;
#pragma unroll
        for (int d = 0; d < 64; ++d) o[d] += p * u2f(vr[d]);
    }
    float inv = 1.f / sum;
#pragma unroll
    for (int d = 0; d < 64; ++d) qp[d] = f2bf(o[d] * inv);
}

// ---------------------------------------------------------------------------
// Naive LN: one thread per row. x = LN(x + res) * w[woff+h] + b[woff+h]
// ---------------------------------------------------------------------------
__global__ __launch_bounds__(256) void k_ln(
        u16* __restrict__ x, const u16* __restrict__ res, int rld,
        const void* __restrict__ w, const void* __restrict__ b, size_t woff,
        int nrows, const int* __restrict__ flag)
{
    const int bf = *flag;
    int row = blockIdx.x * 256 + threadIdx.x;
    if (row >= nrows) return;
    u16* xr = x + (size_t)row * H_;
    const u16* rr = res + (size_t)row * rld;

    float s = 0.f;
    for (int h = 0; h < H_; ++h) s += u2f(xr[h]) + u2f(rr[h]);
    float mu = s * (1.f / H_);
    float s2 = 0.f;
    for (int h = 0; h < H_; ++h) {
        float d = u2f(xr[h]) + u2f(rr[h]) - mu;
        s2 += d * d;
    }
    float rstd = rsqrtf(s2 * (1.f / H_) + 1e-5f);
    for (int h = 0; h < H_; ++h) {
        float d = u2f(xr[h]) + u2f(rr[h]) - mu;
        xr[h] = f2bf(d * rstd * ldf(w, woff + h, bf) + ldf(b, woff + h, bf));
    }
}

// ---------------------------------------------------------------------------
// Final projection: Cf[m*64+o] = sum_k x[m*32768+k] * W_out[o*32768+k]
// One wave per output element; shuffle-reduce; fp32 store.
// ---------------------------------------------------------------------------
__global__ __launch_bounds__(64) void k_fingemm(
        const u16* __restrict__ A, const void* __restrict__ W,
        float* __restrict__ Cf, const int* __restrict__ flag)
{
    const int bf = *flag;
    int out = blockIdx.x;            // 0 .. 32767
    int m = out >> 6, o = out & 63;
    int lane = threadIdx.x;
    const u16* a = A + (size_t)m * 32768;
    size_t wbase = (size_t)o * 32768;
    float acc = 0.f;
    for (int k = lane; k < 32768; k += 64)
        acc += u2f(a[k]) * ldf(W, wbase + k, bf);
#pragma unroll
    for (int off = 32; off > 0; off >>= 1) acc += __shfl_down(acc, off, 64);
    if (lane == 0) Cf[out] = acc;
}

// ---------------------------------------------------------------------------
// Naive final LN: one thread per row of 64. *** fp32 OUTPUT *** (the
// reference returns fp32; R2-R8's bf16 output was the bug: correct bf16
// bits read as fp32 pairs == the deterministic 5.41 error).
// ---------------------------------------------------------------------------
__global__ __launch_bounds__(256) void k_lnf(
        const float* __restrict__ C, const void* __restrict__ b_out,
        const void* __restrict__ w, const void* __restrict__ b,
        float* __restrict__ out, const int* __restrict__ flag)
{
    const int bf = *flag;
    int row = blockIdx.x * 256 + threadIdx.x;
    if (row >= T_) return;
    const float* cr = C + (size_t)row * OUT_;

    float s = 0.f;
    for (int o = 0; o < OUT_; ++o) s += cr[o] + ldf(b_out, o, bf);
    float mu = s * (1.f / OUT_);
    float s2 = 0.f;
    for (int o = 0; o < OUT_; ++o) {
        float d = cr[o] + ldf(b_out, o, bf) - mu;
        s2 += d * d;
    }
    float rstd = rsqrtf(s2 * (1.f / OUT_) + 1e-5f);
    for (int o = 0; o < OUT_; ++o) {
        float d = cr[o] + ldf(b_out, o, bf) - mu;
        out[(size_t)row * OUT_ + o] = d * rstd * ldf(w, o, bf) + ldf(b, o, bf);
    }
}

// ---------------------------------------------------------------------------
extern "C" void kernel_launch(void* const* d_in, const int* in_sizes, int n_in,
                              void* d_out, int out_size, void* d_ws, size_t ws_size,
                              hipStream_t stream)
{
    // Canonical (setup_inputs dict-order) element counts:
    static const int szA[23] = {
        1048576, 195072, 65536, 4096, 256, 98304, 256, 393216, 1536,
        131072, 512, 512, 512, 262144, 1024, 262144, 512, 512, 512,
        2097152, 64, 64, 64};
    // Sorted-key (jax pytree) element counts:
    static const int szB[23] = {
        4096, 2097152, 98304, 195072, 256, 64, 256, 1024, 262144, 512,
        262144, 1048576, 512, 512, 512, 512, 64, 64, 65536, 512, 131072,
        1536, 393216};
    // mapB[canonical index] = position in sorted-key layout
    static const int mapB[23] = {
        11, 3, 18, 0, 4, 2, 6, 22, 21, 20, 19, 13, 12, 8, 7, 10, 9,
        15, 14, 1, 5, 16, 17};

    bool isA = (n_in >= 23), isB = (n_in >= 23);
    for (int i = 0; i < 23 && i < n_in; ++i) {
        if (in_sizes[i] != szA[i]) isA = false;
        if (in_sizes[i] != szB[i]) isB = false;
    }
    const void* in[23];
    for (int i = 0; i < 23; ++i)
        in[i] = (!isA && isB) ? d_in[mapB[i]] : d_in[i];

    const void* forest = in[0];
    const int*  adj    = (const int*)in[1];
    const int*  no     = (const int*)in[2];
    const void* W_in   = in[3];
    const void* b_in   = in[4];
    const void* W_pos  = in[5];
    const void* b_pos  = in[6];
    const void* qkv_w  = in[7];
    const void* qkv_b  = in[8];
    const void* outp_w = in[9];
    const void* outp_b = in[10];
    const void* ln1_w  = in[11];
    const void* ln1_b  = in[12];
    const void* ff1_w  = in[13];
    const void* ff1_b  = in[14];
    const void* ff2_w  = in[15];
    const void* ff2_b  = in[16];
    const void* ln2_w  = in[17];
    const void* ln2_b  = in[18];
    const void* W_out  = in[19];
    const void* b_out  = in[20];
    const void* lnf_w  = in[21];
    const void* lnf_b  = in[22];

    // ---- ws layout, sized from ws_size (never writes past it) ----
    int* flag = (int*)d_ws;                                   // 64 B region
    int* mask = (int*)((char*)d_ws + 64);                     // TOK ints
    u16* xb   = (u16*)((char*)d_ws + 64 + (size_t)TOK_ * 4);  // TOK x 256
    u16* cbuf = xb + (size_t)TOK_ * H_;                       // rows x 768
    size_t used = 64 + (size_t)TOK_ * 4 + (size_t)TOK_ * H_ * 2;
    size_t avail = (ws_size > used) ? ws_size - used : 0;
    size_t max_rows = avail / (768 * 2);
    int rc = (int)((max_rows / 128) * 128);
    if (rc > TOK_) rc = TOK_;
    if (rc < 128) rc = 128;

    // dtype probe on resolved ln1_w (all-ones)
    k_detect<<<1, 1, 0, stream>>>(ln1_w, flag);

    // pos bitmasks (literal reference scan), then x0
    k_pos<<<(T_ + 255) / 256, 256, 0, stream>>>(adj, no, mask);
    k_init_x<<<TOK_, 256, 0, stream>>>(forest, mask, W_in, b_in, W_pos, b_pos,
                                       xb, flag);

    // transformer layers, chunked over whole trees
    for (int R0 = 0; R0 < TOK_; R0 += rc) {
        int rows = (TOK_ - R0 < rc) ? (TOK_ - R0) : rc;
        u16* xc  = xb + (size_t)R0 * H_;
        u16* qc  = cbuf;                       // rows x 768
        u16* hc  = cbuf;                       // rows x 512 (reuse, qc dead)
        u16* h2c = cbuf + (size_t)rows * 512;  // rows x 256 (tail)

        for (int l = 0; l < L_; ++l) {
            // qkv = x @ qkv_w[l]^T + qkv_b[l]
            k_gemm_naive<<<((size_t)rows * 768 + 255) / 256, 256, 0, stream>>>(
                xc, H_, qkv_w, (size_t)l * 768 * 256, 256,
                qkv_b, (size_t)l * 768, qc, 768, rows, 768, 256, 0, flag);
            // attention in place (O over q slice)
            k_attn<<<((size_t)rows * HEADS_ + 255) / 256, 256, 0, stream>>>(qc, rows);
            // proj = O @ outp_w[l]^T + outp_b[l] -> cols 256..511
            k_gemm_naive<<<((size_t)rows * 256 + 255) / 256, 256, 0, stream>>>(
                qc, 768, outp_w, (size_t)l * 256 * 256, 256,
                outp_b, (size_t)l * 256, qc + 256, 768, rows, 256, 256, 0, flag);
            // x = LN(x + proj)
            k_ln<<<(rows + 255) / 256, 256, 0, stream>>>(
                xc, qc + 256, 768, ln1_w, ln1_b, (size_t)l * 256, rows, flag);
            // h = relu(x @ ff1_w[l]^T + ff1_b[l])
            k_gemm_naive<<<((size_t)rows * 512 + 255) / 256, 256, 0, stream>>>(
                xc, H_, ff1_w, (size_t)l * 512 * 256, 256,
                ff1_b, (size_t)l * 512, hc, 512, rows, 512, 256, 1, flag);
            // h2 = h @ ff2_w[l]^T + ff2_b[l]
            k_gemm_naive<<<((size_t)rows * 256 + 255) / 256, 256, 0, stream>>>(
                hc, 512, ff2_w, (size_t)l * 256 * 512, 512,
                ff2_b, (size_t)l * 256, h2c, 256, rows, 256, 512, 0, flag);
            // x = LN(x + h2)
            k_ln<<<(rows + 255) / 256, 256, 0, stream>>>(
                xc, h2c, 256, ln2_w, ln2_b, (size_t)l * 256, rows, flag);
        }
    }

    // final: Cf = x.reshape(512, 32768) @ W_out^T  (one wave per output)
    float* Cf = (float*)cbuf;                  // 128 KiB, cbuf dead
    k_fingemm<<<T_ * OUT_, 64, 0, stream>>>(xb, W_out, Cf, flag);
    // out = LN(Cf + b_out) -> fp32 output
    k_lnf<<<(T_ + 255) / 256, 256, 0, stream>>>(Cf, b_out, lnf_w, lnf_b,
                                                (float*)d_out, flag);
}

// Round 10
// 3327.597 us; speedup vs baseline: 77.8129x; 77.8129x over previous
//
#include <hip/hip_runtime.h>

#define B_    128
#define A_    4
#define N_    128
#define F_IN_ 16
#define H_    256
#define HEADS_ 4
#define FF_   512
#define OUT_  64
#define BF_   3
#define L_    2
#define T_    512          // B*A
#define E_    127          // N-1
#define DH_   64
#define P_    384          // N*BF
#define TOK_  65536        // T*N

typedef unsigned short u16;

__device__ __forceinline__ float u2f(u16 u) {
    return __uint_as_float(((unsigned)u) << 16);
}
__device__ __forceinline__ u16 f2bf(float f) {
    unsigned u = __float_as_uint(f);
    unsigned r = (u + 0x7fffu + ((u >> 16) & 1u)) >> 16;
    return (u16)r;
}

// ---------------------------------------------------------------------------
// Literal transcription of the reference pos_encoding scan (verified R9).
// ---------------------------------------------------------------------------
__global__ __launch_bounds__(256) void k_pos(
        const int* __restrict__ adj, const int* __restrict__ no,
        int* __restrict__ mask)
{
    int t = blockIdx.x * 256 + threadIdx.x;
    if (t >= T_) return;
    const int* noT = no + (size_t)t * N_;
    int mx = noT[0];
    for (int i = 1; i < N_; ++i) mx = max(mx, noT[i]);
    int* mk = mask + (size_t)t * N_;
    mk[0] = 0;
    for (int r = 0; r < E_; ++r) {
        const int* e = adj + ((size_t)t * E_ + r) * 3;
        int pg = e[0], cg = e[1], sl = e[2];
        if (pg < 0 || cg < 0) continue;
        int p = pg - t * N_;
        int c = cg - t * N_;
        if (p < 0 || p >= N_ || c < 0 || c >= N_) continue;
        int sli = sl + 1;
        sli = sli < 0 ? 0 : (sli > BF_ - 1 ? BF_ - 1 : sli);
        int pd = mx - noT[p];
        int bit = pd * BF_ + sli;
        if (bit >= 0 && bit < 31)
            mk[c] = mk[p] | (1 << bit);
        else
            mk[c] = mk[p];
    }
}

// ---------------------------------------------------------------------------
// x0 = forest @ W_in^T + b_in + pos @ W_pos^T + b_pos  -> bf16 x  (verified)
// ---------------------------------------------------------------------------
__global__ __launch_bounds__(256) void k_init_x(
        const float* __restrict__ forest, const int* __restrict__ mask,
        const float* __restrict__ W_in, const float* __restrict__ b_in,
        const float* __restrict__ W_pos, const float* __restrict__ b_pos,
        u16* __restrict__ x)
{
    int tn = blockIdx.x;
    int h = threadIdx.x;

    float acc = b_in[h] + b_pos[h];
#pragma unroll
    for (int f = 0; f < F_IN_; ++f)
        acc += forest[(size_t)tn * F_IN_ + f] * W_in[(size_t)h * F_IN_ + f];

    unsigned mk = (unsigned)mask[tn];
#pragma unroll
    for (int bit = 0; bit < 15; ++bit)
        if (mk & (1u << bit))
            acc += W_pos[(size_t)h * P_ + bit];

    x[(size_t)tn * H_ + h] = f2bf(acc);
}

// ---------------------------------------------------------------------------
// Tiled GEMM (bit-verified vs naive in R3<->R7 cross-check):
// C[m,n] = act( sum_k A[m,k] * Bw[boff + n*ldb + k] + bias[biasoff+n] )
// A bf16 (lda), Bw fp32 weights, fp32 accumulate. 64x64 tile, BK=32, 256 thr.
// mode 0: C bf16 store; mode 1: C fp32 atomicAdd (split-K), bias ignored.
// ---------------------------------------------------------------------------
__global__ __launch_bounds__(256) void k_gemm(
        const u16* __restrict__ A, int lda,
        const float* __restrict__ Bw, int ldb, size_t boff,
        const float* __restrict__ bias, size_t biasoff,
        void* __restrict__ Cv, int ldc,
        int kchunk, int relu, int mode)
{
    __shared__ float As[32][68];
    __shared__ float Bs[32][68];

    int tid = threadIdx.x;
    int tx = tid & 15, ty = tid >> 4;
    int m0 = blockIdx.x * 64;
    int n0 = blockIdx.y * 64;
    int k0 = blockIdx.z * kchunk;
    int kend = k0 + kchunk;

    int ar = tid >> 3;            // 0..31
    int ak = (tid & 7) << 2;      // 0,4,...,28

    float acc[4][4];
#pragma unroll
    for (int i = 0; i < 4; ++i)
#pragma unroll
        for (int j = 0; j < 4; ++j) acc[i][j] = 0.f;

    for (int k = k0; k < kend; k += 32) {
        __syncthreads();
#pragma unroll
        for (int pass = 0; pass < 2; ++pass) {
            int row = ar + pass * 32;
            ushort4 ua = *reinterpret_cast<const ushort4*>(
                &A[(size_t)(m0 + row) * lda + k + ak]);
            As[ak + 0][row] = u2f(ua.x); As[ak + 1][row] = u2f(ua.y);
            As[ak + 2][row] = u2f(ua.z); As[ak + 3][row] = u2f(ua.w);
            float4 vb = *reinterpret_cast<const float4*>(
                &Bw[boff + (size_t)(n0 + row) * ldb + k + ak]);
            Bs[ak + 0][row] = vb.x; Bs[ak + 1][row] = vb.y;
            Bs[ak + 2][row] = vb.z; Bs[ak + 3][row] = vb.w;
        }
        __syncthreads();
#pragma unroll
        for (int kk = 0; kk < 32; ++kk) {
            float4 av = *reinterpret_cast<const float4*>(&As[kk][ty << 2]);
            float4 bv = *reinterpret_cast<const float4*>(&Bs[kk][tx << 2]);
            float a4[4] = {av.x, av.y, av.z, av.w};
            float b4[4] = {bv.x, bv.y, bv.z, bv.w};
#pragma unroll
            for (int i = 0; i < 4; ++i)
#pragma unroll
                for (int j = 0; j < 4; ++j)
                    acc[i][j] += a4[i] * b4[j];
        }
    }

#pragma unroll
    for (int i = 0; i < 4; ++i) {
        int m = m0 + (ty << 2) + i;
#pragma unroll
        for (int j = 0; j < 4; ++j) {
            int n = n0 + (tx << 2) + j;
            float v = acc[i][j];
            if (mode == 1) {
                atomicAdd(&((float*)Cv)[(size_t)m * ldc + n], v);
            } else {
                if (bias) v += bias[biasoff + n];
                if (relu) v = fmaxf(v, 0.f);
                ((u16*)Cv)[(size_t)m * ldc + n] = f2bf(v);
            }
        }
    }
}

// ---------------------------------------------------------------------------
// Attention per (tree, head), LDS-staged K/V (bit-verified in R3<->R7).
// block=128 (thread = query row); online softmax; O -> q slice in place.
// ---------------------------------------------------------------------------
__global__ __launch_bounds__(128) void k_attn(u16* __restrict__ qkv)
{
    __shared__ u16 Ks[128 * 64];
    __shared__ u16 Vs[128 * 64];

    int blk = blockIdx.x;
    int t = blk >> 2, hd = blk & 3;
    int tid = threadIdx.x;
    u16* base = qkv + (size_t)t * 128 * 768;

    for (int idx = tid; idx < 128 * 16; idx += 128) {
        int r = idx >> 4, d4 = (idx & 15) << 2;
        *reinterpret_cast<ushort4*>(&Ks[r * 64 + d4]) =
            *reinterpret_cast<const ushort4*>(&base[r * 768 + 256 + hd * 64 + d4]);
        *reinterpret_cast<ushort4*>(&Vs[r * 64 + d4]) =
            *reinterpret_cast<const ushort4*>(&base[r * 768 + 512 + hd * 64 + d4]);
    }

    float q[64];
    u16* qrow = base + tid * 768 + hd * 64;
#pragma unroll
    for (int d4 = 0; d4 < 64; d4 += 4) {
        ushort4 v = *reinterpret_cast<const ushort4*>(&qrow[d4]);
        q[d4] = u2f(v.x); q[d4 + 1] = u2f(v.y);
        q[d4 + 2] = u2f(v.z); q[d4 + 3] = u2f(v.w);
    }
    __syncthreads();

    float m = -3e38f, l = 0.f, o[64];
#pragma unroll
    for (int d = 0; d < 64; ++d) o[d] = 0.f;

    for (int c0 = 0; c0 < 128; c0 += 16) {
        float s[16];
        float cm = -3e38f;
#pragma unroll
        for (int j = 0; j < 16; ++j) {
            const u16* kr = &Ks[(c0 + j) * 64];
            float a = 0.f;
#pragma unroll
            for (int d = 0; d < 64; ++d) a += q[d] * u2f(kr[d]);
            s[j] = a * 0.125f;
            cm = fmaxf(cm, s[j]);
        }
        float mn = fmaxf(m, cm);
        float scale = __expf(m - mn);
        l *= scale;
#pragma unroll
        for (int d = 0; d < 64; ++d) o[d] *= scale;
#pragma unroll
        for (int j = 0; j < 16; ++j) {
            float p = __expf(s[j] - mn);
            l += p;
            const u16* vr = &Vs[(c0 + j) * 64];
#pragma unroll
            for (int d = 0; d < 64; ++d) o[d] += p * u2f(vr[d]);
        }
        m = mn;
    }
    float inv = 1.f / l;
#pragma unroll
    for (int d4 = 0; d4 < 64; d4 += 4) {
        ushort4 v;
        v.x = f2bf(o[d4] * inv);     v.y = f2bf(o[d4 + 1] * inv);
        v.z = f2bf(o[d4 + 2] * inv); v.w = f2bf(o[d4 + 3] * inv);
        *reinterpret_cast<ushort4*>(&qrow[d4]) = v;
    }
}

// ---------------------------------------------------------------------------
// x = LayerNorm(x + res) * w[woff+h] + b[woff+h]  (block reduce, verified)
// ---------------------------------------------------------------------------
__global__ __launch_bounds__(256) void k_ln(
        u16* __restrict__ x, const u16* __restrict__ res, int rld,
        const float* __restrict__ w, const float* __restrict__ b, size_t woff)
{
    __shared__ float red[4];
    int row = blockIdx.x, h = threadIdx.x;
    float v = u2f(x[(size_t)row * H_ + h]) + u2f(res[(size_t)row * rld + h]);

    float s = v;
#pragma unroll
    for (int o = 32; o > 0; o >>= 1) s += __shfl_down(s, o, 64);
    int lane = h & 63, wid = h >> 6;
    if (lane == 0) red[wid] = s;
    __syncthreads();
    float mu = (red[0] + red[1] + red[2] + red[3]) * (1.f / 256.f);
    __syncthreads();
    float d = v - mu;
    float s2 = d * d;
#pragma unroll
    for (int o = 32; o > 0; o >>= 1) s2 += __shfl_down(s2, o, 64);
    if (lane == 0) red[wid] = s2;
    __syncthreads();
    float var = (red[0] + red[1] + red[2] + red[3]) * (1.f / 256.f);
    x[(size_t)row * H_ + h] =
        f2bf(d * rsqrtf(var + 1e-5f) * w[woff + h] + b[woff + h]);
}

// ---------------------------------------------------------------------------
__global__ __launch_bounds__(256) void k_zero(float* __restrict__ p, int n)
{
    int i = blockIdx.x * 256 + threadIdx.x;
    if (i < n) p[i] = 0.f;
}

// ---------------------------------------------------------------------------
// out = LayerNorm(Cf[row,:] + b_out) * lnf_w + lnf_b -> fp32 (verified R9)
// ---------------------------------------------------------------------------
__global__ __launch_bounds__(256) void k_lnf(
        const float* __restrict__ C, const float* __restrict__ b_out,
        const float* __restrict__ w, const float* __restrict__ b,
        float* __restrict__ out)
{
    int row = blockIdx.x * 256 + threadIdx.x;
    if (row >= T_) return;
    const float* cr = C + (size_t)row * OUT_;

    float s = 0.f;
    for (int o = 0; o < OUT_; ++o) s += cr[o] + b_out[o];
    float mu = s * (1.f / OUT_);
    float s2 = 0.f;
    for (int o = 0; o < OUT_; ++o) {
        float d = cr[o] + b_out[o] - mu;
        s2 += d * d;
    }
    float rstd = rsqrtf(s2 * (1.f / OUT_) + 1e-5f);
    for (int o = 0; o < OUT_; ++o) {
        float d = cr[o] + b_out[o] - mu;
        out[(size_t)row * OUT_ + o] = d * rstd * w[o] + b[o];
    }
}

// ---------------------------------------------------------------------------
extern "C" void kernel_launch(void* const* d_in, const int* in_sizes, int n_in,
                              void* d_out, int out_size, void* d_ws, size_t ws_size,
                              hipStream_t stream)
{
    // size-signature resolver (canonical dict order confirmed in R9; the
    // sorted-key fallback is kept as free insurance)
    static const int szA[23] = {
        1048576, 195072, 65536, 4096, 256, 98304, 256, 393216, 1536,
        131072, 512, 512, 512, 262144, 1024, 262144, 512, 512, 512,
        2097152, 64, 64, 64};
    static const int mapB[23] = {
        11, 3, 18, 0, 4, 2, 6, 22, 21, 20, 19, 13, 12, 8, 7, 10, 9,
        15, 14, 1, 5, 16, 17};
    bool isA = (n_in >= 23);
    for (int i = 0; i < 23 && i < n_in; ++i)
        if (in_sizes[i] != szA[i]) isA = false;
    const void* in[23];
    for (int i = 0; i < 23; ++i)
        in[i] = isA ? d_in[i] : d_in[mapB[i]];

    const float* forest = (const float*)in[0];
    const int*   adj    = (const int*)in[1];
    const int*   no     = (const int*)in[2];
    const float* W_in   = (const float*)in[3];
    const float* b_in   = (const float*)in[4];
    const float* W_pos  = (const float*)in[5];
    const float* b_pos  = (const float*)in[6];
    const float* qkv_w  = (const float*)in[7];
    const float* qkv_b  = (const float*)in[8];
    const float* outp_w = (const float*)in[9];
    const float* outp_b = (const float*)in[10];
    const float* ln1_w  = (const float*)in[11];
    const float* ln1_b  = (const float*)in[12];
    const float* ff1_w  = (const float*)in[13];
    const float* ff1_b  = (const float*)in[14];
    const float* ff2_w  = (const float*)in[15];
    const float* ff2_b  = (const float*)in[16];
    const float* ln2_w  = (const float*)in[17];
    const float* ln2_b  = (const float*)in[18];
    const float* W_out  = (const float*)in[19];
    const float* b_out  = (const float*)in[20];
    const float* lnf_w  = (const float*)in[21];
    const float* lnf_b  = (const float*)in[22];

    // ---- ws layout, sized from ws_size (never writes past it) ----
    int* mask = (int*)d_ws;                              // TOK ints (256 KiB)
    u16* xb   = (u16*)((char*)d_ws + (size_t)TOK_ * 4);  // TOK x 256 (32 MiB)
    u16* cbuf = xb + (size_t)TOK_ * H_;                  // chunk buf rows x 768
    size_t used = (size_t)TOK_ * 4 + (size_t)TOK_ * H_ * 2;
    size_t avail = (ws_size > used) ? ws_size - used : 0;
    size_t max_rows = avail / (768 * 2);
    int rc = (int)((max_rows / 128) * 128);
    if (rc > TOK_) rc = TOK_;
    if (rc < 128) rc = 128;

    // pos bitmasks (literal reference scan), then x0
    k_pos<<<(T_ + 255) / 256, 256, 0, stream>>>(adj, no, mask);
    k_init_x<<<TOK_, 256, 0, stream>>>(forest, mask, W_in, b_in, W_pos, b_pos, xb);

    // transformer layers, chunked over whole trees (tiled GEMMs)
    for (int R0 = 0; R0 < TOK_; R0 += rc) {
        int rows = (TOK_ - R0 < rc) ? (TOK_ - R0) : rc;   // multiple of 128
        u16* xc  = xb + (size_t)R0 * H_;
        u16* qc  = cbuf;                       // rows x 768
        u16* hc  = cbuf;                       // rows x 512 (reuse, qc dead)
        u16* h2c = cbuf + (size_t)rows * 512;  // rows x 256 (tail)

        for (int l = 0; l < L_; ++l) {
            // qkv = x @ qkv_w[l]^T + qkv_b[l]
            k_gemm<<<dim3(rows / 64, 768 / 64, 1), 256, 0, stream>>>(
                xc, H_, qkv_w, 256, (size_t)l * 768 * 256,
                qkv_b, (size_t)l * 768, qc, 768, 256, 0, 0);
            // attention in place (O over q slice)
            k_attn<<<(rows / 128) * HEADS_, 128, 0, stream>>>(qc);
            // proj = O @ outp_w[l]^T + outp_b[l] -> cols 256..511
            k_gemm<<<dim3(rows / 64, 256 / 64, 1), 256, 0, stream>>>(
                qc, 768, outp_w, 256, (size_t)l * 256 * 256,
                outp_b, (size_t)l * 256, qc + 256, 768, 256, 0, 0);
            // x = LN(x + proj)
            k_ln<<<rows, 256, 0, stream>>>(xc, qc + 256, 768,
                                           ln1_w, ln1_b, (size_t)l * 256);
            // h = relu(x @ ff1_w[l]^T + ff1_b[l])
            k_gemm<<<dim3(rows / 64, 512 / 64, 1), 256, 0, stream>>>(
                xc, H_, ff1_w, 256, (size_t)l * 512 * 256,
                ff1_b, (size_t)l * 512, hc, 512, 256, 1, 0);
            // h2 = h @ ff2_w[l]^T + ff2_b[l]
            k_gemm<<<dim3(rows / 64, 256 / 64, 1), 256, 0, stream>>>(
                hc, 512, ff2_w, 512, (size_t)l * 256 * 512,
                ff2_b, (size_t)l * 256, h2c, 256, 512, 0, 0);
            // x = LN(x + h2)
            k_ln<<<rows, 256, 0, stream>>>(xc, h2c, 256,
                                           ln2_w, ln2_b, (size_t)l * 256);
        }
    }

    // final: Cf = x.reshape(512, 32768) @ W_out^T (split-K=32, atomic fp32)
    float* Cf = (float*)cbuf;                  // 128 KiB, cbuf dead
    k_zero<<<(T_ * OUT_ + 255) / 256, 256, 0, stream>>>(Cf, T_ * OUT_);
    k_gemm<<<dim3(T_ / 64, OUT_ / 64, 32), 256, 0, stream>>>(
        xb, 32768, W_out, 32768, 0, nullptr, 0,
        Cf, OUT_, 1024, 0, 1);
    // out = LN(Cf + b_out) -> fp32
    k_lnf<<<(T_ + 255) / 256, 256, 0, stream>>>(Cf, b_out, lnf_w, lnf_b,
                                                (float*)d_out);
}

// Round 11
// 1892.726 us; speedup vs baseline: 136.8026x; 1.7581x over previous
//
#include <hip/hip_runtime.h>

#define B_    128
#define A_    4
#define N_    128
#define F_IN_ 16
#define H_    256
#define HEADS_ 4
#define FF_   512
#define OUT_  64
#define BF_   3
#define L_    2
#define T_    512          // B*A
#define E_    127          // N-1
#define DH_   64
#define P_    384          // N*BF
#define TOK_  65536        // T*N

typedef unsigned short u16;
typedef __attribute__((ext_vector_type(8))) short bf16x8;   // 8 bf16 = 4 VGPR
typedef __attribute__((ext_vector_type(4))) float f32x4;

__device__ __forceinline__ float u2f(u16 u) {
    return __uint_as_float(((unsigned)u) << 16);
}
__device__ __forceinline__ u16 f2bf(float f) {
    unsigned u = __float_as_uint(f);
    unsigned r = (u + 0x7fffu + ((u >> 16) & 1u)) >> 16;
    return (u16)r;
}

// ---------------------------------------------------------------------------
// fp32 -> bf16 weight conversion (grid-stride)
// ---------------------------------------------------------------------------
__global__ __launch_bounds__(256) void k_cvt(
        const float* __restrict__ src, u16* __restrict__ dst, int n)
{
    for (int i = blockIdx.x * 256 + threadIdx.x; i < n; i += gridDim.x * 256)
        dst[i] = f2bf(src[i]);
}

// ---------------------------------------------------------------------------
// Literal transcription of the reference pos_encoding scan (verified R9).
// ---------------------------------------------------------------------------
__global__ __launch_bounds__(256) void k_pos(
        const int* __restrict__ adj, const int* __restrict__ no,
        int* __restrict__ mask)
{
    int t = blockIdx.x * 256 + threadIdx.x;
    if (t >= T_) return;
    const int* noT = no + (size_t)t * N_;
    int mx = noT[0];
    for (int i = 1; i < N_; ++i) mx = max(mx, noT[i]);
    int* mk = mask + (size_t)t * N_;
    mk[0] = 0;
    for (int r = 0; r < E_; ++r) {
        const int* e = adj + ((size_t)t * E_ + r) * 3;
        int pg = e[0], cg = e[1], sl = e[2];
        if (pg < 0 || cg < 0) continue;
        int p = pg - t * N_;
        int c = cg - t * N_;
        if (p < 0 || p >= N_ || c < 0 || c >= N_) continue;
        int sli = sl + 1;
        sli = sli < 0 ? 0 : (sli > BF_ - 1 ? BF_ - 1 : sli);
        int pd = mx - noT[p];
        int bit = pd * BF_ + sli;
        if (bit >= 0 && bit < 31)
            mk[c] = mk[p] | (1 << bit);
        else
            mk[c] = mk[p];
    }
}

// ---------------------------------------------------------------------------
// x0 = forest @ W_in^T + b_in + pos @ W_pos^T + b_pos  -> bf16 x  (verified)
// ---------------------------------------------------------------------------
__global__ __launch_bounds__(256) void k_init_x(
        const float* __restrict__ forest, const int* __restrict__ mask,
        const float* __restrict__ W_in, const float* __restrict__ b_in,
        const float* __restrict__ W_pos, const float* __restrict__ b_pos,
        u16* __restrict__ x)
{
    int tn = blockIdx.x;
    int h = threadIdx.x;

    float acc = b_in[h] + b_pos[h];
#pragma unroll
    for (int f = 0; f < F_IN_; ++f)
        acc += forest[(size_t)tn * F_IN_ + f] * W_in[(size_t)h * F_IN_ + f];

    unsigned mk = (unsigned)mask[tn];
#pragma unroll
    for (int bit = 0; bit < 15; ++bit)
        if (mk & (1u << bit))
            acc += W_pos[(size_t)h * P_ + bit];

    x[(size_t)tn * H_ + h] = f2bf(acc);
}

// ---------------------------------------------------------------------------
// MFMA GEMM: C[m,n] = act(sum_k A[m,k]*Bw[n,k] + bias[biasoff+n])
// A bf16 (lda), Bw bf16 (ldb, pre-converted weights), fp32 acc via MFMA.
// BM=BN=128, BK=32; 256 thr = 4 waves in 2x2; wave = 4x4 tiles of 16x16.
// Fragment layouts (guide §3, m89/m91/m120-verified):
//   A/B frag: [row/col = lane&15][k = (lane>>4)*8 + j]  (8 contiguous bf16)
//   C/D:      col = lane&15, row = (lane>>4)*4 + reg
// LDS row stride 40 shorts (80 B): 16B-aligned b128 reads, <=2-way banks.
// ---------------------------------------------------------------------------
__global__ __launch_bounds__(256) void k_gemm_mfma(
        const u16* __restrict__ A, int lda,
        const u16* __restrict__ Bw, int ldb,
        const float* __restrict__ bias, size_t biasoff,
        u16* __restrict__ C, int ldc,
        int K, int relu)
{
    __shared__ u16 As[128][40];
    __shared__ u16 Bs[128][40];

    int tid = threadIdx.x;
    int wid = tid >> 6, lane = tid & 63;
    int ln15 = lane & 15, quad = lane >> 4;
    int wm = (wid >> 1) * 64, wn = (wid & 1) * 64;
    size_t m0 = (size_t)blockIdx.x * 128;
    size_t n0 = (size_t)blockIdx.y * 128;

    f32x4 acc[4][4];
#pragma unroll
    for (int i = 0; i < 4; ++i)
#pragma unroll
        for (int j = 0; j < 4; ++j)
#pragma unroll
            for (int r = 0; r < 4; ++r) acc[i][j][r] = 0.f;

    for (int k0 = 0; k0 < K; k0 += 32) {
        __syncthreads();
#pragma unroll
        for (int s = 0; s < 2; ++s) {
            int idx = tid + s * 256;        // 0..511
            int r = idx >> 2;               // 0..127
            int kq = (idx & 3) * 8;         // 0,8,16,24
            *reinterpret_cast<uint4*>(&As[r][kq]) =
                *reinterpret_cast<const uint4*>(&A[(m0 + r) * (size_t)lda + k0 + kq]);
            *reinterpret_cast<uint4*>(&Bs[r][kq]) =
                *reinterpret_cast<const uint4*>(&Bw[(n0 + r) * (size_t)ldb + k0 + kq]);
        }
        __syncthreads();

        bf16x8 af[4], bfr[4];
#pragma unroll
        for (int i = 0; i < 4; ++i)
            af[i] = *reinterpret_cast<const bf16x8*>(&As[wm + i * 16 + ln15][quad * 8]);
#pragma unroll
        for (int j = 0; j < 4; ++j)
            bfr[j] = *reinterpret_cast<const bf16x8*>(&Bs[wn + j * 16 + ln15][quad * 8]);
#pragma unroll
        for (int i = 0; i < 4; ++i)
#pragma unroll
            for (int j = 0; j < 4; ++j)
                acc[i][j] = __builtin_amdgcn_mfma_f32_16x16x32_bf16(
                    af[i], bfr[j], acc[i][j], 0, 0, 0);
    }

#pragma unroll
    for (int i = 0; i < 4; ++i) {
#pragma unroll
        for (int j = 0; j < 4; ++j) {
            int col = (int)n0 + wn + j * 16 + ln15;
            float bv = bias ? bias[biasoff + col] : 0.f;
#pragma unroll
            for (int r = 0; r < 4; ++r) {
                int row = (int)m0 + wm + i * 16 + quad * 4 + r;
                float v = acc[i][j][r] + bv;
                if (relu) v = fmaxf(v, 0.f);
                C[(size_t)row * ldc + col] = f2bf(v);
            }
        }
    }
}

// ---------------------------------------------------------------------------
// SIMT tiled GEMM — kept for the final skinny projection (split-K atomic).
// ---------------------------------------------------------------------------
__global__ __launch_bounds__(256) void k_gemm(
        const u16* __restrict__ A, int lda,
        const float* __restrict__ Bw, int ldb, size_t boff,
        float* __restrict__ C, int ldc, int kchunk)
{
    __shared__ float As[32][68];
    __shared__ float Bs[32][68];

    int tid = threadIdx.x;
    int tx = tid & 15, ty = tid >> 4;
    int m0 = blockIdx.x * 64;
    int n0 = blockIdx.y * 64;
    int k0 = blockIdx.z * kchunk;
    int kend = k0 + kchunk;

    int ar = tid >> 3;
    int ak = (tid & 7) << 2;

    float acc[4][4];
#pragma unroll
    for (int i = 0; i < 4; ++i)
#pragma unroll
        for (int j = 0; j < 4; ++j) acc[i][j] = 0.f;

    for (int k = k0; k < kend; k += 32) {
        __syncthreads();
#pragma unroll
        for (int pass = 0; pass < 2; ++pass) {
            int row = ar + pass * 32;
            ushort4 ua = *reinterpret_cast<const ushort4*>(
                &A[(size_t)(m0 + row) * lda + k + ak]);
            As[ak + 0][row] = u2f(ua.x); As[ak + 1][row] = u2f(ua.y);
            As[ak + 2][row] = u2f(ua.z); As[ak + 3][row] = u2f(ua.w);
            float4 vb = *reinterpret_cast<const float4*>(
                &Bw[boff + (size_t)(n0 + row) * ldb + k + ak]);
            Bs[ak + 0][row] = vb.x; Bs[ak + 1][row] = vb.y;
            Bs[ak + 2][row] = vb.z; Bs[ak + 3][row] = vb.w;
        }
        __syncthreads();
#pragma unroll
        for (int kk = 0; kk < 32; ++kk) {
            float4 av = *reinterpret_cast<const float4*>(&As[kk][ty << 2]);
            float4 bv = *reinterpret_cast<const float4*>(&Bs[kk][tx << 2]);
            float a4[4] = {av.x, av.y, av.z, av.w};
            float b4[4] = {bv.x, bv.y, bv.z, bv.w};
#pragma unroll
            for (int i = 0; i < 4; ++i)
#pragma unroll
                for (int j = 0; j < 4; ++j)
                    acc[i][j] += a4[i] * b4[j];
        }
    }

#pragma unroll
    for (int i = 0; i < 4; ++i) {
        int m = m0 + (ty << 2) + i;
#pragma unroll
        for (int j = 0; j < 4; ++j) {
            int n = n0 + (tx << 2) + j;
            atomicAdd(&C[(size_t)m * ldc + n], acc[i][j]);
        }
    }
}

// ---------------------------------------------------------------------------
// Attention per (tree, head), LDS K/V, online softmax; ushort4 LDS reads.
// ---------------------------------------------------------------------------
__global__ __launch_bounds__(128) void k_attn(u16* __restrict__ qkv)
{
    __shared__ u16 Ks[128 * 64];
    __shared__ u16 Vs[128 * 64];

    int blk = blockIdx.x;
    int t = blk >> 2, hd = blk & 3;
    int tid = threadIdx.x;
    u16* base = qkv + (size_t)t * 128 * 768;

    for (int idx = tid; idx < 128 * 16; idx += 128) {
        int r = idx >> 4, d4 = (idx & 15) << 2;
        *reinterpret_cast<ushort4*>(&Ks[r * 64 + d4]) =
            *reinterpret_cast<const ushort4*>(&base[r * 768 + 256 + hd * 64 + d4]);
        *reinterpret_cast<ushort4*>(&Vs[r * 64 + d4]) =
            *reinterpret_cast<const ushort4*>(&base[r * 768 + 512 + hd * 64 + d4]);
    }

    float q[64];
    u16* qrow = base + tid * 768 + hd * 64;
#pragma unroll
    for (int d4 = 0; d4 < 64; d4 += 4) {
        ushort4 v = *reinterpret_cast<const ushort4*>(&qrow[d4]);
        q[d4] = u2f(v.x); q[d4 + 1] = u2f(v.y);
        q[d4 + 2] = u2f(v.z); q[d4 + 3] = u2f(v.w);
    }
    __syncthreads();

    float m = -3e38f, l = 0.f, o[64];
#pragma unroll
    for (int d = 0; d < 64; ++d) o[d] = 0.f;

    for (int c0 = 0; c0 < 128; c0 += 16) {
        float s[16];
        float cm = -3e38f;
#pragma unroll
        for (int j = 0; j < 16; ++j) {
            const u16* kr = &Ks[(c0 + j) * 64];
            float a = 0.f;
#pragma unroll
            for (int d4 = 0; d4 < 64; d4 += 4) {
                ushort4 kv = *reinterpret_cast<const ushort4*>(&kr[d4]);
                a += q[d4] * u2f(kv.x) + q[d4 + 1] * u2f(kv.y)
                   + q[d4 + 2] * u2f(kv.z) + q[d4 + 3] * u2f(kv.w);
            }
            s[j] = a * 0.125f;
            cm = fmaxf(cm, s[j]);
        }
        float mn = fmaxf(m, cm);
        float scale = __expf(m - mn);
        l *= scale;
#pragma unroll
        for (int d = 0; d < 64; ++d) o[d] *= scale;
#pragma unroll
        for (int j = 0; j < 16; ++j) {
            float p = __expf(s[j] - mn);
            l += p;
            const u16* vr = &Vs[(c0 + j) * 64];
#pragma unroll
            for (int d4 = 0; d4 < 64; d4 += 4) {
                ushort4 vv = *reinterpret_cast<const ushort4*>(&vr[d4]);
                o[d4]     += p * u2f(vv.x);
                o[d4 + 1] += p * u2f(vv.y);
                o[d4 + 2] += p * u2f(vv.z);
                o[d4 + 3] += p * u2f(vv.w);
            }
        }
        m = mn;
    }
    float inv = 1.f / l;
#pragma unroll
    for (int d4 = 0; d4 < 64; d4 += 4) {
        ushort4 v;
        v.x = f2bf(o[d4] * inv);     v.y = f2bf(o[d4 + 1] * inv);
        v.z = f2bf(o[d4 + 2] * inv); v.w = f2bf(o[d4 + 3] * inv);
        *reinterpret_cast<ushort4*>(&qrow[d4]) = v;
    }
}

// ---------------------------------------------------------------------------
// x = LayerNorm(x + res) * w[woff+h] + b[woff+h]  (block reduce, verified)
// ---------------------------------------------------------------------------
__global__ __launch_bounds__(256) void k_ln(
        u16* __restrict__ x, const u16* __restrict__ res, int rld,
        const float* __restrict__ w, const float* __restrict__ b, size_t woff)
{
    __shared__ float red[4];
    int row = blockIdx.x, h = threadIdx.x;
    float v = u2f(x[(size_t)row * H_ + h]) + u2f(res[(size_t)row * rld + h]);

    float s = v;
#pragma unroll
    for (int o = 32; o > 0; o >>= 1) s += __shfl_down(s, o, 64);
    int lane = h & 63, wid = h >> 6;
    if (lane == 0) red[wid] = s;
    __syncthreads();
    float mu = (red[0] + red[1] + red[2] + red[3]) * (1.f / 256.f);
    __syncthreads();
    float d = v - mu;
    float s2 = d * d;
#pragma unroll
    for (int o = 32; o > 0; o >>= 1) s2 += __shfl_down(s2, o, 64);
    if (lane == 0) red[wid] = s2;
    __syncthreads();
    float var = (red[0] + red[1] + red[2] + red[3]) * (1.f / 256.f);
    x[(size_t)row * H_ + h] =
        f2bf(d * rsqrtf(var + 1e-5f) * w[woff + h] + b[woff + h]);
}

// ---------------------------------------------------------------------------
__global__ __launch_bounds__(256) void k_zero(float* __restrict__ p, int n)
{
    int i = blockIdx.x * 256 + threadIdx.x;
    if (i < n) p[i] = 0.f;
}

// ---------------------------------------------------------------------------
// out = LayerNorm(Cf[row,:] + b_out) * lnf_w + lnf_b -> fp32 (verified R9)
// ---------------------------------------------------------------------------
__global__ __launch_bounds__(256) void k_lnf(
        const float* __restrict__ C, const float* __restrict__ b_out,
        const float* __restrict__ w, const float* __restrict__ b,
        float* __restrict__ out)
{
    int row = blockIdx.x * 256 + threadIdx.x;
    if (row >= T_) return;
    const float* cr = C + (size_t)row * OUT_;

    float s = 0.f;
    for (int o = 0; o < OUT_; ++o) s += cr[o] + b_out[o];
    float mu = s * (1.f / OUT_);
    float s2 = 0.f;
    for (int o = 0; o < OUT_; ++o) {
        float d = cr[o] + b_out[o] - mu;
        s2 += d * d;
    }
    float rstd = rsqrtf(s2 * (1.f / OUT_) + 1e-5f);
    for (int o = 0; o < OUT_; ++o) {
        float d = cr[o] + b_out[o] - mu;
        out[(size_t)row * OUT_ + o] = d * rstd * w[o] + b[o];
    }
}

// ---------------------------------------------------------------------------
extern "C" void kernel_launch(void* const* d_in, const int* in_sizes, int n_in,
                              void* d_out, int out_size, void* d_ws, size_t ws_size,
                              hipStream_t stream)
{
    static const int szA[23] = {
        1048576, 195072, 65536, 4096, 256, 98304, 256, 393216, 1536,
        131072, 512, 512, 512, 262144, 1024, 262144, 512, 512, 512,
        2097152, 64, 64, 64};
    static const int mapB[23] = {
        11, 3, 18, 0, 4, 2, 6, 22, 21, 20, 19, 13, 12, 8, 7, 10, 9,
        15, 14, 1, 5, 16, 17};
    bool isA = (n_in >= 23);
    for (int i = 0; i < 23 && i < n_in; ++i)
        if (in_sizes[i] != szA[i]) isA = false;
    const void* in[23];
    for (int i = 0; i < 23; ++i)
        in[i] = isA ? d_in[i] : d_in[mapB[i]];

    const float* forest = (const float*)in[0];
    const int*   adj    = (const int*)in[1];
    const int*   no     = (const int*)in[2];
    const float* W_in   = (const float*)in[3];
    const float* b_in   = (const float*)in[4];
    const float* W_pos  = (const float*)in[5];
    const float* b_pos  = (const float*)in[6];
    const float* qkv_w  = (const float*)in[7];
    const float* qkv_b  = (const float*)in[8];
    const float* outp_w = (const float*)in[9];
    const float* outp_b = (const float*)in[10];
    const float* ln1_w  = (const float*)in[11];
    const float* ln1_b  = (const float*)in[12];
    const float* ff1_w  = (const float*)in[13];
    const float* ff1_b  = (const float*)in[14];
    const float* ff2_w  = (const float*)in[15];
    const float* ff2_b  = (const float*)in[16];
    const float* ln2_w  = (const float*)in[17];
    const float* ln2_b  = (const float*)in[18];
    const float* W_out  = (const float*)in[19];
    const float* b_out  = (const float*)in[20];
    const float* lnf_w  = (const float*)in[21];
    const float* lnf_b  = (const float*)in[22];

    // ---- ws layout: mask | xb | wb (bf16 weights) | cbuf (chunk) ----
    int* mask = (int*)d_ws;                              // 256 KiB
    u16* xb   = (u16*)((char*)d_ws + (size_t)TOK_ * 4);  // 32 MiB
    u16* wb   = xb + (size_t)TOK_ * H_;                  // 2 MiB bf16 weights
    const size_t WB_QKV = 0;
    const size_t WB_OUT = 393216;
    const size_t WB_FF1 = 524288;
    const size_t WB_FF2 = 786432;
    u16* cbuf = wb + 1048576;                            // rows x 768 bf16
    size_t used = (size_t)TOK_ * 4 + (size_t)TOK_ * H_ * 2 + 1048576 * 2;
    size_t avail = (ws_size > used) ? ws_size - used : 0;
    size_t max_rows = avail / (768 * 2);
    int rc = (int)((max_rows / 128) * 128);
    if (rc > TOK_) rc = TOK_;
    if (rc < 128) rc = 128;

    // weight conversion fp32 -> bf16 (per launch; ws re-poisoned each call)
    k_cvt<<<512, 256, 0, stream>>>(qkv_w,  wb + WB_QKV, 393216);
    k_cvt<<<256, 256, 0, stream>>>(outp_w, wb + WB_OUT, 131072);
    k_cvt<<<512, 256, 0, stream>>>(ff1_w,  wb + WB_FF1, 262144);
    k_cvt<<<512, 256, 0, stream>>>(ff2_w,  wb + WB_FF2, 262144);

    // pos bitmasks, then x0
    k_pos<<<(T_ + 255) / 256, 256, 0, stream>>>(adj, no, mask);
    k_init_x<<<TOK_, 256, 0, stream>>>(forest, mask, W_in, b_in, W_pos, b_pos, xb);

    // transformer layers, chunked over whole trees (MFMA GEMMs)
    for (int R0 = 0; R0 < TOK_; R0 += rc) {
        int rows = (TOK_ - R0 < rc) ? (TOK_ - R0) : rc;   // multiple of 128
        u16* xc  = xb + (size_t)R0 * H_;
        u16* qc  = cbuf;                       // rows x 768
        u16* hc  = cbuf;                       // rows x 512 (reuse, qc dead)
        u16* h2c = cbuf + (size_t)rows * 512;  // rows x 256 (tail)

        for (int l = 0; l < L_; ++l) {
            // qkv = x @ qkv_w[l]^T + qkv_b[l]
            k_gemm_mfma<<<dim3(rows / 128, 768 / 128), 256, 0, stream>>>(
                xc, H_, wb + WB_QKV + (size_t)l * 768 * 256, 256,
                qkv_b, (size_t)l * 768, qc, 768, 256, 0);
            // attention in place (O over q slice)
            k_attn<<<(rows / 128) * HEADS_, 128, 0, stream>>>(qc);
            // proj = O @ outp_w[l]^T + outp_b[l] -> cols 256..511
            k_gemm_mfma<<<dim3(rows / 128, 256 / 128), 256, 0, stream>>>(
                qc, 768, wb + WB_OUT + (size_t)l * 256 * 256, 256,
                outp_b, (size_t)l * 256, qc + 256, 768, 256, 0);
            // x = LN(x + proj)
            k_ln<<<rows, 256, 0, stream>>>(xc, qc + 256, 768,
                                           ln1_w, ln1_b, (size_t)l * 256);
            // h = relu(x @ ff1_w[l]^T + ff1_b[l])
            k_gemm_mfma<<<dim3(rows / 128, 512 / 128), 256, 0, stream>>>(
                xc, H_, wb + WB_FF1 + (size_t)l * 512 * 256, 256,
                ff1_b, (size_t)l * 512, hc, 512, 256, 1);
            // h2 = h @ ff2_w[l]^T + ff2_b[l]
            k_gemm_mfma<<<dim3(rows / 128, 256 / 128), 256, 0, stream>>>(
                hc, 512, wb + WB_FF2 + (size_t)l * 256 * 512, 512,
                ff2_b, (size_t)l * 256, h2c, 256, 512, 0);
            // x = LN(x + h2)
            k_ln<<<rows, 256, 0, stream>>>(xc, h2c, 256,
                                           ln2_w, ln2_b, (size_t)l * 256);
        }
    }

    // final: Cf = x.reshape(512, 32768) @ W_out^T (split-K=32, atomic fp32)
    float* Cf = (float*)cbuf;                  // 128 KiB, cbuf dead
    k_zero<<<(T_ * OUT_ + 255) / 256, 256, 0, stream>>>(Cf, T_ * OUT_);
    k_gemm<<<dim3(T_ / 64, OUT_ / 64, 32), 256, 0, stream>>>(
        xb, 32768, W_out, 32768, 0, Cf, OUT_, 1024);
    // out = LN(Cf + b_out) -> fp32
    k_lnf<<<(T_ + 255) / 256, 256, 0, stream>>>(Cf, b_out, lnf_w, lnf_b,
                                                (float*)d_out);
}

// Round 12
// 1152.856 us; speedup vs baseline: 224.5986x; 1.6418x over previous
//
#include <hip/hip_runtime.h>

#define B_    128
#define A_    4
#define N_    128
#define F_IN_ 16
#define H_    256
#define HEADS_ 4
#define FF_   512
#define OUT_  64
#define BF_   3
#define L_    2
#define T_    512          // B*A
#define E_    127          // N-1
#define DH_   64
#define P_    384          // N*BF
#define TOK_  65536        // T*N

typedef unsigned short u16;
typedef __attribute__((ext_vector_type(8))) short bf16x8;   // 8 bf16 = 4 VGPR
typedef __attribute__((ext_vector_type(4))) float f32x4;

__device__ __forceinline__ float u2f(u16 u) {
    return __uint_as_float(((unsigned)u) << 16);
}
__device__ __forceinline__ u16 f2bf(float f) {
    unsigned u = __float_as_uint(f);
    unsigned r = (u + 0x7fffu + ((u >> 16) & 1u)) >> 16;
    return (u16)r;
}

// ---------------------------------------------------------------------------
// fp32 -> bf16 weight conversion (grid-stride)
// ---------------------------------------------------------------------------
__global__ __launch_bounds__(256) void k_cvt(
        const float* __restrict__ src, u16* __restrict__ dst, int n)
{
    for (int i = blockIdx.x * 256 + threadIdx.x; i < n; i += gridDim.x * 256)
        dst[i] = f2bf(src[i]);
}

// ---------------------------------------------------------------------------
// Literal transcription of the reference pos_encoding scan (verified R9).
// ---------------------------------------------------------------------------
__global__ __launch_bounds__(256) void k_pos(
        const int* __restrict__ adj, const int* __restrict__ no,
        int* __restrict__ mask)
{
    int t = blockIdx.x * 256 + threadIdx.x;
    if (t >= T_) return;
    const int* noT = no + (size_t)t * N_;
    int mx = noT[0];
    for (int i = 1; i < N_; ++i) mx = max(mx, noT[i]);
    int* mk = mask + (size_t)t * N_;
    mk[0] = 0;
    for (int r = 0; r < E_; ++r) {
        const int* e = adj + ((size_t)t * E_ + r) * 3;
        int pg = e[0], cg = e[1], sl = e[2];
        if (pg < 0 || cg < 0) continue;
        int p = pg - t * N_;
        int c = cg - t * N_;
        if (p < 0 || p >= N_ || c < 0 || c >= N_) continue;
        int sli = sl + 1;
        sli = sli < 0 ? 0 : (sli > BF_ - 1 ? BF_ - 1 : sli);
        int pd = mx - noT[p];
        int bit = pd * BF_ + sli;
        if (bit >= 0 && bit < 31)
            mk[c] = mk[p] | (1 << bit);
        else
            mk[c] = mk[p];
    }
}

// ---------------------------------------------------------------------------
// x0 = forest @ W_in^T + b_in + pos @ W_pos^T + b_pos  -> bf16 x  (verified)
// ---------------------------------------------------------------------------
__global__ __launch_bounds__(256) void k_init_x(
        const float* __restrict__ forest, const int* __restrict__ mask,
        const float* __restrict__ W_in, const float* __restrict__ b_in,
        const float* __restrict__ W_pos, const float* __restrict__ b_pos,
        u16* __restrict__ x)
{
    int tn = blockIdx.x;
    int h = threadIdx.x;

    float acc = b_in[h] + b_pos[h];
#pragma unroll
    for (int f = 0; f < F_IN_; ++f)
        acc += forest[(size_t)tn * F_IN_ + f] * W_in[(size_t)h * F_IN_ + f];

    unsigned mk = (unsigned)mask[tn];
#pragma unroll
    for (int bit = 0; bit < 15; ++bit)
        if (mk & (1u << bit))
            acc += W_pos[(size_t)h * P_ + bit];

    x[(size_t)tn * H_ + h] = f2bf(acc);
}

// ---------------------------------------------------------------------------
// MFMA GEMM (verified R11): C[m,n] = act(sum_k A[m,k]*Bw[n,k] + bias[..n])
// BM=BN=128, BK=32; 256 thr = 4 waves 2x2; wave = 4x4 tiles of 16x16.
// ---------------------------------------------------------------------------
__global__ __launch_bounds__(256) void k_gemm_mfma(
        const u16* __restrict__ A, int lda,
        const u16* __restrict__ Bw, int ldb,
        const float* __restrict__ bias, size_t biasoff,
        u16* __restrict__ C, int ldc,
        int K, int relu)
{
    __shared__ __align__(16) u16 As[128][40];
    __shared__ __align__(16) u16 Bs[128][40];

    int tid = threadIdx.x;
    int wid = tid >> 6, lane = tid & 63;
    int ln15 = lane & 15, quad = lane >> 4;
    int wm = (wid >> 1) * 64, wn = (wid & 1) * 64;
    size_t m0 = (size_t)blockIdx.x * 128;
    size_t n0 = (size_t)blockIdx.y * 128;

    f32x4 acc[4][4];
#pragma unroll
    for (int i = 0; i < 4; ++i)
#pragma unroll
        for (int j = 0; j < 4; ++j)
#pragma unroll
            for (int r = 0; r < 4; ++r) acc[i][j][r] = 0.f;

    for (int k0 = 0; k0 < K; k0 += 32) {
        __syncthreads();
#pragma unroll
        for (int s = 0; s < 2; ++s) {
            int idx = tid + s * 256;        // 0..511
            int r = idx >> 2;               // 0..127
            int kq = (idx & 3) * 8;         // 0,8,16,24
            *reinterpret_cast<uint4*>(&As[r][kq]) =
                *reinterpret_cast<const uint4*>(&A[(m0 + r) * (size_t)lda + k0 + kq]);
            *reinterpret_cast<uint4*>(&Bs[r][kq]) =
                *reinterpret_cast<const uint4*>(&Bw[(n0 + r) * (size_t)ldb + k0 + kq]);
        }
        __syncthreads();

        bf16x8 af[4], bfr[4];
#pragma unroll
        for (int i = 0; i < 4; ++i)
            af[i] = *reinterpret_cast<const bf16x8*>(&As[wm + i * 16 + ln15][quad * 8]);
#pragma unroll
        for (int j = 0; j < 4; ++j)
            bfr[j] = *reinterpret_cast<const bf16x8*>(&Bs[wn + j * 16 + ln15][quad * 8]);
#pragma unroll
        for (int i = 0; i < 4; ++i)
#pragma unroll
            for (int j = 0; j < 4; ++j)
                acc[i][j] = __builtin_amdgcn_mfma_f32_16x16x32_bf16(
                    af[i], bfr[j], acc[i][j], 0, 0, 0);
    }

#pragma unroll
    for (int i = 0; i < 4; ++i) {
#pragma unroll
        for (int j = 0; j < 4; ++j) {
            int col = (int)n0 + wn + j * 16 + ln15;
            float bv = bias ? bias[biasoff + col] : 0.f;
#pragma unroll
            for (int r = 0; r < 4; ++r) {
                int row = (int)m0 + wm + i * 16 + quad * 4 + r;
                float v = acc[i][j][r] + bv;
                if (relu) v = fmaxf(v, 0.f);
                C[(size_t)row * ldc + col] = f2bf(v);
            }
        }
    }
}

// ---------------------------------------------------------------------------
// SIMT tiled GEMM — final skinny projection (split-K atomic, verified).
// ---------------------------------------------------------------------------
__global__ __launch_bounds__(256) void k_gemm(
        const u16* __restrict__ A, int lda,
        const float* __restrict__ Bw, int ldb, size_t boff,
        float* __restrict__ C, int ldc, int kchunk)
{
    __shared__ float As[32][68];
    __shared__ float Bs[32][68];

    int tid = threadIdx.x;
    int tx = tid & 15, ty = tid >> 4;
    int m0 = blockIdx.x * 64;
    int n0 = blockIdx.y * 64;
    int k0 = blockIdx.z * kchunk;
    int kend = k0 + kchunk;

    int ar = tid >> 3;
    int ak = (tid & 7) << 2;

    float acc[4][4];
#pragma unroll
    for (int i = 0; i < 4; ++i)
#pragma unroll
        for (int j = 0; j < 4; ++j) acc[i][j] = 0.f;

    for (int k = k0; k < kend; k += 32) {
        __syncthreads();
#pragma unroll
        for (int pass = 0; pass < 2; ++pass) {
            int row = ar + pass * 32;
            ushort4 ua = *reinterpret_cast<const ushort4*>(
                &A[(size_t)(m0 + row) * lda + k + ak]);
            As[ak + 0][row] = u2f(ua.x); As[ak + 1][row] = u2f(ua.y);
            As[ak + 2][row] = u2f(ua.z); As[ak + 3][row] = u2f(ua.w);
            float4 vb = *reinterpret_cast<const float4*>(
                &Bw[boff + (size_t)(n0 + row) * ldb + k + ak]);
            Bs[ak + 0][row] = vb.x; Bs[ak + 1][row] = vb.y;
            Bs[ak + 2][row] = vb.z; Bs[ak + 3][row] = vb.w;
        }
        __syncthreads();
#pragma unroll
        for (int kk = 0; kk < 32; ++kk) {
            float4 av = *reinterpret_cast<const float4*>(&As[kk][ty << 2]);
            float4 bv = *reinterpret_cast<const float4*>(&Bs[kk][tx << 2]);
            float a4[4] = {av.x, av.y, av.z, av.w};
            float b4[4] = {bv.x, bv.y, bv.z, bv.w};
#pragma unroll
            for (int i = 0; i < 4; ++i)
#pragma unroll
                for (int j = 0; j < 4; ++j)
                    acc[i][j] += a4[i] * b4[j];
        }
    }

#pragma unroll
    for (int i = 0; i < 4; ++i) {
        int m = m0 + (ty << 2) + i;
#pragma unroll
        for (int j = 0; j < 4; ++j) {
            int n = n0 + (tx << 2) + j;
            atomicAdd(&C[(size_t)m * ldc + n], acc[i][j]);
        }
    }
}

// ---------------------------------------------------------------------------
// MFMA attention per (tree, head). 256 thr = 4 waves; wave owns 32 Q rows.
// S = QK^T via mfma (C-layout regs) -> rowwise softmax (shfl_xor over the
// quad's 16 lanes + register loop over col-tiles) -> normalized P to LDS
// (C-layout -> A-layout round trip) -> O = P @ V^T via mfma -> store.
// K staged row-major [128][72]; V staged TRANSPOSED [64][136] (B-operand
// needs V^T[d][j]). Fragment layouts identical to k_gemm_mfma (HW-verified).
// ---------------------------------------------------------------------------
__global__ __launch_bounds__(256) void k_attn_mfma(u16* __restrict__ qkv)
{
    __shared__ __align__(16) u16 Ks[128 * 72];
    __shared__ __align__(16) u16 Vt[64 * 136];
    __shared__ __align__(16) u16 Ps[4][32 * 136];

    int blk = blockIdx.x;
    int t = blk >> 2, hd = blk & 3;
    int tid = threadIdx.x;
    int w = tid >> 6, lane = tid & 63;
    int ln15 = lane & 15, quad = lane >> 4;
    u16* base = qkv + (size_t)t * 128 * 768;

    // stage K row-major, V transposed
    for (int idx = tid; idx < 128 * 16; idx += 256) {
        int r = idx >> 4, d4 = (idx & 15) << 2;
        *reinterpret_cast<ushort4*>(&Ks[r * 72 + d4]) =
            *reinterpret_cast<const ushort4*>(&base[r * 768 + 256 + hd * 64 + d4]);
        ushort4 v = *reinterpret_cast<const ushort4*>(&base[r * 768 + 512 + hd * 64 + d4]);
        Vt[(d4 + 0) * 136 + r] = v.x;
        Vt[(d4 + 1) * 136 + r] = v.y;
        Vt[(d4 + 2) * 136 + r] = v.z;
        Vt[(d4 + 3) * 136 + r] = v.w;
    }

    // Q A-frags straight from global (wave-private rows)
    bf16x8 qf[2][2];
#pragma unroll
    for (int i = 0; i < 2; ++i)
#pragma unroll
        for (int kk = 0; kk < 2; ++kk)
            qf[i][kk] = *reinterpret_cast<const bf16x8*>(
                &base[(size_t)(w * 32 + i * 16 + ln15) * 768 + hd * 64 + kk * 32 + quad * 8]);
    __syncthreads();

    // S = Q K^T  (2 row-tiles x 8 col-tiles, K-dim 64 = 2 steps)
    f32x4 sa[2][8];
#pragma unroll
    for (int i = 0; i < 2; ++i)
#pragma unroll
        for (int j = 0; j < 8; ++j)
#pragma unroll
            for (int r = 0; r < 4; ++r) sa[i][j][r] = 0.f;

#pragma unroll
    for (int j = 0; j < 8; ++j)
#pragma unroll
        for (int kk = 0; kk < 2; ++kk) {
            bf16x8 kf = *reinterpret_cast<const bf16x8*>(
                &Ks[(j * 16 + ln15) * 72 + kk * 32 + quad * 8]);
            sa[0][j] = __builtin_amdgcn_mfma_f32_16x16x32_bf16(qf[0][kk], kf, sa[0][j], 0, 0, 0);
            sa[1][j] = __builtin_amdgcn_mfma_f32_16x16x32_bf16(qf[1][kk], kf, sa[1][j], 0, 0, 0);
        }

    // rowwise softmax; write normalized P (bf16) into wave-private LDS
    const float scale = 0.125f;
#pragma unroll
    for (int i = 0; i < 2; ++i) {
#pragma unroll
        for (int r = 0; r < 4; ++r) {
            float m = -3e38f;
#pragma unroll
            for (int j = 0; j < 8; ++j) m = fmaxf(m, sa[i][j][r]);
            m = fmaxf(m, __shfl_xor(m, 1, 64));
            m = fmaxf(m, __shfl_xor(m, 2, 64));
            m = fmaxf(m, __shfl_xor(m, 4, 64));
            m = fmaxf(m, __shfl_xor(m, 8, 64));
            m *= scale;
            float p[8];
            float l = 0.f;
#pragma unroll
            for (int j = 0; j < 8; ++j) {
                p[j] = __expf(sa[i][j][r] * scale - m);
                l += p[j];
            }
            l += __shfl_xor(l, 1, 64);
            l += __shfl_xor(l, 2, 64);
            l += __shfl_xor(l, 4, 64);
            l += __shfl_xor(l, 8, 64);
            float inv = 1.f / l;
            int row = i * 16 + quad * 4 + r;
#pragma unroll
            for (int j = 0; j < 8; ++j)
                Ps[w][row * 136 + j * 16 + ln15] = f2bf(p[j] * inv);
        }
    }

    // O = P @ V^T  (2 row-tiles x 4 d-tiles, K-dim 128 = 4 steps)
    f32x4 oa[2][4];
#pragma unroll
    for (int i = 0; i < 2; ++i)
#pragma unroll
        for (int jt = 0; jt < 4; ++jt)
#pragma unroll
            for (int r = 0; r < 4; ++r) oa[i][jt][r] = 0.f;

#pragma unroll
    for (int ks = 0; ks < 4; ++ks) {
        bf16x8 pf0 = *reinterpret_cast<const bf16x8*>(
            &Ps[w][(0 + ln15) * 136 + ks * 32 + quad * 8]);
        bf16x8 pf1 = *reinterpret_cast<const bf16x8*>(
            &Ps[w][(16 + ln15) * 136 + ks * 32 + quad * 8]);
#pragma unroll
        for (int jt = 0; jt < 4; ++jt) {
            bf16x8 vf = *reinterpret_cast<const bf16x8*>(
                &Vt[(jt * 16 + ln15) * 136 + ks * 32 + quad * 8]);
            oa[0][jt] = __builtin_amdgcn_mfma_f32_16x16x32_bf16(pf0, vf, oa[0][jt], 0, 0, 0);
            oa[1][jt] = __builtin_amdgcn_mfma_f32_16x16x32_bf16(pf1, vf, oa[1][jt], 0, 0, 0);
        }
    }

    // store O over the q slice (C-layout)
#pragma unroll
    for (int i = 0; i < 2; ++i)
#pragma unroll
        for (int jt = 0; jt < 4; ++jt)
#pragma unroll
            for (int r = 0; r < 4; ++r) {
                int row = w * 32 + i * 16 + quad * 4 + r;
                int d = jt * 16 + ln15;
                base[(size_t)row * 768 + hd * 64 + d] = f2bf(oa[i][jt][r]);
            }
}

// ---------------------------------------------------------------------------
// x = LayerNorm(x + res) * w[woff+h] + b[woff+h]  (block reduce, verified)
// ---------------------------------------------------------------------------
__global__ __launch_bounds__(256) void k_ln(
        u16* __restrict__ x, const u16* __restrict__ res, int rld,
        const float* __restrict__ w, const float* __restrict__ b, size_t woff)
{
    __shared__ float red[4];
    int row = blockIdx.x, h = threadIdx.x;
    float v = u2f(x[(size_t)row * H_ + h]) + u2f(res[(size_t)row * rld + h]);

    float s = v;
#pragma unroll
    for (int o = 32; o > 0; o >>= 1) s += __shfl_down(s, o, 64);
    int lane = h & 63, wid = h >> 6;
    if (lane == 0) red[wid] = s;
    __syncthreads();
    float mu = (red[0] + red[1] + red[2] + red[3]) * (1.f / 256.f);
    __syncthreads();
    float d = v - mu;
    float s2 = d * d;
#pragma unroll
    for (int o = 32; o > 0; o >>= 1) s2 += __shfl_down(s2, o, 64);
    if (lane == 0) red[wid] = s2;
    __syncthreads();
    float var = (red[0] + red[1] + red[2] + red[3]) * (1.f / 256.f);
    x[(size_t)row * H_ + h] =
        f2bf(d * rsqrtf(var + 1e-5f) * w[woff + h] + b[woff + h]);
}

// ---------------------------------------------------------------------------
__global__ __launch_bounds__(256) void k_zero(float* __restrict__ p, int n)
{
    int i = blockIdx.x * 256 + threadIdx.x;
    if (i < n) p[i] = 0.f;
}

// ---------------------------------------------------------------------------
// out = LayerNorm(Cf[row,:] + b_out) * lnf_w + lnf_b -> fp32 (verified R9)
// ---------------------------------------------------------------------------
__global__ __launch_bounds__(256) void k_lnf(
        const float* __restrict__ C, const float* __restrict__ b_out,
        const float* __restrict__ w, const float* __restrict__ b,
        float* __restrict__ out)
{
    int row = blockIdx.x * 256 + threadIdx.x;
    if (row >= T_) return;
    const float* cr = C + (size_t)row * OUT_;

    float s = 0.f;
    for (int o = 0; o < OUT_; ++o) s += cr[o] + b_out[o];
    float mu = s * (1.f / OUT_);
    float s2 = 0.f;
    for (int o = 0; o < OUT_; ++o) {
        float d = cr[o] + b_out[o] - mu;
        s2 += d * d;
    }
    float rstd = rsqrtf(s2 * (1.f / OUT_) + 1e-5f);
    for (int o = 0; o < OUT_; ++o) {
        float d = cr[o] + b_out[o] - mu;
        out[(size_t)row * OUT_ + o] = d * rstd * w[o] + b[o];
    }
}

// ---------------------------------------------------------------------------
extern "C" void kernel_launch(void* const* d_in, const int* in_sizes, int n_in,
                              void* d_out, int out_size, void* d_ws, size_t ws_size,
                              hipStream_t stream)
{
    static const int szA[23] = {
        1048576, 195072, 65536, 4096, 256, 98304, 256, 393216, 1536,
        131072, 512, 512, 512, 262144, 1024, 262144, 512, 512, 512,
        2097152, 64, 64, 64};
    static const int mapB[23] = {
        11, 3, 18, 0, 4, 2, 6, 22, 21, 20, 19, 13, 12, 8, 7, 10, 9,
        15, 14, 1, 5, 16, 17};
    bool isA = (n_in >= 23);
    for (int i = 0; i < 23 && i < n_in; ++i)
        if (in_sizes[i] != szA[i]) isA = false;
    const void* in[23];
    for (int i = 0; i < 23; ++i)
        in[i] = isA ? d_in[i] : d_in[mapB[i]];

    const float* forest = (const float*)in[0];
    const int*   adj    = (const int*)in[1];
    const int*   no     = (const int*)in[2];
    const float* W_in   = (const float*)in[3];
    const float* b_in   = (const float*)in[4];
    const float* W_pos  = (const float*)in[5];
    const float* b_pos  = (const float*)in[6];
    const float* qkv_w  = (const float*)in[7];
    const float* qkv_b  = (const float*)in[8];
    const float* outp_w = (const float*)in[9];
    const float* outp_b = (const float*)in[10];
    const float* ln1_w  = (const float*)in[11];
    const float* ln1_b  = (const float*)in[12];
    const float* ff1_w  = (const float*)in[13];
    const float* ff1_b  = (const float*)in[14];
    const float* ff2_w  = (const float*)in[15];
    const float* ff2_b  = (const float*)in[16];
    const float* ln2_w  = (const float*)in[17];
    const float* ln2_b  = (const float*)in[18];
    const float* W_out  = (const float*)in[19];
    const float* b_out  = (const float*)in[20];
    const float* lnf_w  = (const float*)in[21];
    const float* lnf_b  = (const float*)in[22];

    // ---- ws layout: mask | xb | wb (bf16 weights) | cbuf (chunk) ----
    int* mask = (int*)d_ws;                              // 256 KiB
    u16* xb   = (u16*)((char*)d_ws + (size_t)TOK_ * 4);  // 32 MiB
    u16* wb   = xb + (size_t)TOK_ * H_;                  // 2 MiB bf16 weights
    const size_t WB_QKV = 0;
    const size_t WB_OUT = 393216;
    const size_t WB_FF1 = 524288;
    const size_t WB_FF2 = 786432;
    u16* cbuf = wb + 1048576;                            // rows x 768 bf16
    size_t used = (size_t)TOK_ * 4 + (size_t)TOK_ * H_ * 2 + 1048576 * 2;
    size_t avail = (ws_size > used) ? ws_size - used : 0;
    size_t max_rows = avail / (768 * 2);
    int rc = (int)((max_rows / 128) * 128);
    if (rc > TOK_) rc = TOK_;
    if (rc < 128) rc = 128;

    // weight conversion fp32 -> bf16 (per launch; ws re-poisoned each call)
    k_cvt<<<512, 256, 0, stream>>>(qkv_w,  wb + WB_QKV, 393216);
    k_cvt<<<256, 256, 0, stream>>>(outp_w, wb + WB_OUT, 131072);
    k_cvt<<<512, 256, 0, stream>>>(ff1_w,  wb + WB_FF1, 262144);
    k_cvt<<<512, 256, 0, stream>>>(ff2_w,  wb + WB_FF2, 262144);

    // pos bitmasks, then x0
    k_pos<<<(T_ + 255) / 256, 256, 0, stream>>>(adj, no, mask);
    k_init_x<<<TOK_, 256, 0, stream>>>(forest, mask, W_in, b_in, W_pos, b_pos, xb);

    // transformer layers, chunked over whole trees (MFMA GEMMs + MFMA attn)
    for (int R0 = 0; R0 < TOK_; R0 += rc) {
        int rows = (TOK_ - R0 < rc) ? (TOK_ - R0) : rc;   // multiple of 128
        u16* xc  = xb + (size_t)R0 * H_;
        u16* qc  = cbuf;                       // rows x 768
        u16* hc  = cbuf;                       // rows x 512 (reuse, qc dead)
        u16* h2c = cbuf + (size_t)rows * 512;  // rows x 256 (tail)

        for (int l = 0; l < L_; ++l) {
            // qkv = x @ qkv_w[l]^T + qkv_b[l]
            k_gemm_mfma<<<dim3(rows / 128, 768 / 128), 256, 0, stream>>>(
                xc, H_, wb + WB_QKV + (size_t)l * 768 * 256, 256,
                qkv_b, (size_t)l * 768, qc, 768, 256, 0);
            // attention in place (O over q slice) — MFMA flash
            k_attn_mfma<<<(rows / 128) * HEADS_, 256, 0, stream>>>(qc);
            // proj = O @ outp_w[l]^T + outp_b[l] -> cols 256..511
            k_gemm_mfma<<<dim3(rows / 128, 256 / 128), 256, 0, stream>>>(
                qc, 768, wb + WB_OUT + (size_t)l * 256 * 256, 256,
                outp_b, (size_t)l * 256, qc + 256, 768, 256, 0);
            // x = LN(x + proj)
            k_ln<<<rows, 256, 0, stream>>>(xc, qc + 256, 768,
                                           ln1_w, ln1_b, (size_t)l * 256);
            // h = relu(x @ ff1_w[l]^T + ff1_b[l])
            k_gemm_mfma<<<dim3(rows / 128, 512 / 128), 256, 0, stream>>>(
                xc, H_, wb + WB_FF1 + (size_t)l * 512 * 256, 256,
                ff1_b, (size_t)l * 512, hc, 512, 256, 1);
            // h2 = h @ ff2_w[l]^T + ff2_b[l]
            k_gemm_mfma<<<dim3(rows / 128, 256 / 128), 256, 0, stream>>>(
                hc, 512, wb + WB_FF2 + (size_t)l * 256 * 512, 512,
                ff2_b, (size_t)l * 256, h2c, 256, 512, 0);
            // x = LN(x + h2)
            k_ln<<<rows, 256, 0, stream>>>(xc, h2c, 256,
                                           ln2_w, ln2_b, (size_t)l * 256);
        }
    }

    // final: Cf = x.reshape(512, 32768) @ W_out^T (split-K=32, atomic fp32)
    float* Cf = (float*)cbuf;                  // 128 KiB, cbuf dead
    k_zero<<<(T_ * OUT_ + 255) / 256, 256, 0, stream>>>(Cf, T_ * OUT_);
    k_gemm<<<dim3(T_ / 64, OUT_ / 64, 32), 256, 0, stream>>>(
        xb, 32768, W_out, 32768, 0, Cf, OUT_, 1024);
    // out = LN(Cf + b_out) -> fp32
    k_lnf<<<(T_ + 255) / 256, 256, 0, stream>>>(Cf, b_out, lnf_w, lnf_b,
                                                (float*)d_out);
}

// Round 13
// 815.491 us; speedup vs baseline: 317.5141x; 1.4137x over previous
//
#include <hip/hip_runtime.h>

#define B_    128
#define A_    4
#define N_    128
#define F_IN_ 16
#define H_    256
#define HEADS_ 4
#define FF_   512
#define OUT_  64
#define BF_   3
#define L_    2
#define T_    512          // B*A
#define E_    127          // N-1
#define DH_   64
#define P_    384          // N*BF
#define TOK_  65536        // T*N

typedef unsigned short u16;
typedef __attribute__((ext_vector_type(8))) short bf16x8;   // 8 bf16 = 4 VGPR
typedef __attribute__((ext_vector_type(4))) float f32x4;

__device__ __forceinline__ float u2f(u16 u) {
    return __uint_as_float(((unsigned)u) << 16);
}
__device__ __forceinline__ u16 f2bf(float f) {
    unsigned u = __float_as_uint(f);
    unsigned r = (u + 0x7fffu + ((u >> 16) & 1u)) >> 16;
    return (u16)r;
}

// ---------------------------------------------------------------------------
// fp32 -> bf16 weight conversion (grid-stride)
// ---------------------------------------------------------------------------
__global__ __launch_bounds__(256) void k_cvt(
        const float* __restrict__ src, u16* __restrict__ dst, int n)
{
    for (int i = blockIdx.x * 256 + threadIdx.x; i < n; i += gridDim.x * 256)
        dst[i] = f2bf(src[i]);
}

// ---------------------------------------------------------------------------
// init-weight prep: W_inT[f][h] = W_in[h][f]; W_posT[p][h] = W_pos[h][p]
// (p < 16: only bits 0..14 reachable); bsum = b_in + b_pos.  grid 16 x 256.
// ---------------------------------------------------------------------------
__global__ __launch_bounds__(256) void k_prep(
        const float* __restrict__ W_in, const float* __restrict__ b_in,
        const float* __restrict__ b_pos, const float* __restrict__ W_pos,
        float* __restrict__ W_inT, float* __restrict__ W_posT,
        float* __restrict__ bsum)
{
    int i = blockIdx.x * 256 + threadIdx.x;
    if (i < 4096) W_inT[(i & 15) * 256 + (i >> 4)] = W_in[i];   // i = h*16+f
    if (i < 4096) {
        int p = i >> 8, h = i & 255;
        W_posT[i] = W_pos[(size_t)h * P_ + p];
    }
    if (i < 256) bsum[i] = b_in[i] + b_pos[i];
}

// ---------------------------------------------------------------------------
// Literal transcription of the reference pos_encoding scan (verified R9).
// ---------------------------------------------------------------------------
__global__ __launch_bounds__(256) void k_pos(
        const int* __restrict__ adj, const int* __restrict__ no,
        int* __restrict__ mask)
{
    int t = blockIdx.x * 256 + threadIdx.x;
    if (t >= T_) return;
    const int* noT = no + (size_t)t * N_;
    int mx = noT[0];
    for (int i = 1; i < N_; ++i) mx = max(mx, noT[i]);
    int* mk = mask + (size_t)t * N_;
    mk[0] = 0;
    for (int r = 0; r < E_; ++r) {
        const int* e = adj + ((size_t)t * E_ + r) * 3;
        int pg = e[0], cg = e[1], sl = e[2];
        if (pg < 0 || cg < 0) continue;
        int p = pg - t * N_;
        int c = cg - t * N_;
        if (p < 0 || p >= N_ || c < 0 || c >= N_) continue;
        int sli = sl + 1;
        sli = sli < 0 ? 0 : (sli > BF_ - 1 ? BF_ - 1 : sli);
        int pd = mx - noT[p];
        int bit = pd * BF_ + sli;
        if (bit >= 0 && bit < 31)
            mk[c] = mk[p] | (1 << bit);
        else
            mk[c] = mk[p];
    }
}

// ---------------------------------------------------------------------------
// x0 init, coalesced: block = 4 tokens x 256 channels; weights read once
// (coalesced via transposed copies) and reused for 4 tokens.
// ---------------------------------------------------------------------------
__global__ __launch_bounds__(256) void k_init_x(
        const float* __restrict__ forest, const int* __restrict__ mask,
        const float* __restrict__ W_inT, const float* __restrict__ W_posT,
        const float* __restrict__ bsum, u16* __restrict__ x)
{
    int h = threadIdx.x;
    int t0 = blockIdx.x * 4;

    float wf[16];
#pragma unroll
    for (int f = 0; f < F_IN_; ++f) wf[f] = W_inT[f * 256 + h];
    float bs = bsum[h];

#pragma unroll
    for (int tt = 0; tt < 4; ++tt) {
        int tn = t0 + tt;
        const float* fr = forest + (size_t)tn * F_IN_;
        float acc = bs;
#pragma unroll
        for (int f = 0; f < F_IN_; ++f) acc += fr[f] * wf[f];
        unsigned mk = (unsigned)mask[tn];
        while (mk) {
            int bit = __ffs(mk) - 1;
            mk &= mk - 1;
            acc += W_posT[bit * 256 + h];
        }
        x[(size_t)tn * H_ + h] = f2bf(acc);
    }
}

// ---------------------------------------------------------------------------
// MFMA GEMM (verified R11): C[m,n] = act(sum_k A[m,k]*Bw[n,k] + bias[..n])
// BM=BN=128, BK=32; 256 thr = 4 waves 2x2; wave = 4x4 tiles of 16x16.
// ---------------------------------------------------------------------------
__global__ __launch_bounds__(256) void k_gemm_mfma(
        const u16* __restrict__ A, int lda,
        const u16* __restrict__ Bw, int ldb,
        const float* __restrict__ bias, size_t biasoff,
        u16* __restrict__ C, int ldc,
        int K, int relu)
{
    __shared__ __align__(16) u16 As[128][40];
    __shared__ __align__(16) u16 Bs[128][40];

    int tid = threadIdx.x;
    int wid = tid >> 6, lane = tid & 63;
    int ln15 = lane & 15, quad = lane >> 4;
    int wm = (wid >> 1) * 64, wn = (wid & 1) * 64;
    size_t m0 = (size_t)blockIdx.x * 128;
    size_t n0 = (size_t)blockIdx.y * 128;

    f32x4 acc[4][4];
#pragma unroll
    for (int i = 0; i < 4; ++i)
#pragma unroll
        for (int j = 0; j < 4; ++j)
#pragma unroll
            for (int r = 0; r < 4; ++r) acc[i][j][r] = 0.f;

    for (int k0 = 0; k0 < K; k0 += 32) {
        __syncthreads();
#pragma unroll
        for (int s = 0; s < 2; ++s) {
            int idx = tid + s * 256;        // 0..511
            int r = idx >> 2;               // 0..127
            int kq = (idx & 3) * 8;         // 0,8,16,24
            *reinterpret_cast<uint4*>(&As[r][kq]) =
                *reinterpret_cast<const uint4*>(&A[(m0 + r) * (size_t)lda + k0 + kq]);
            *reinterpret_cast<uint4*>(&Bs[r][kq]) =
                *reinterpret_cast<const uint4*>(&Bw[(n0 + r) * (size_t)ldb + k0 + kq]);
        }
        __syncthreads();

        bf16x8 af[4], bfr[4];
#pragma unroll
        for (int i = 0; i < 4; ++i)
            af[i] = *reinterpret_cast<const bf16x8*>(&As[wm + i * 16 + ln15][quad * 8]);
#pragma unroll
        for (int j = 0; j < 4; ++j)
            bfr[j] = *reinterpret_cast<const bf16x8*>(&Bs[wn + j * 16 + ln15][quad * 8]);
#pragma unroll
        for (int i = 0; i < 4; ++i)
#pragma unroll
            for (int j = 0; j < 4; ++j)
                acc[i][j] = __builtin_amdgcn_mfma_f32_16x16x32_bf16(
                    af[i], bfr[j], acc[i][j], 0, 0, 0);
    }

#pragma unroll
    for (int i = 0; i < 4; ++i) {
#pragma unroll
        for (int j = 0; j < 4; ++j) {
            int col = (int)n0 + wn + j * 16 + ln15;
            float bv = bias ? bias[biasoff + col] : 0.f;
#pragma unroll
            for (int r = 0; r < 4; ++r) {
                int row = (int)m0 + wm + i * 16 + quad * 4 + r;
                float v = acc[i][j][r] + bv;
                if (relu) v = fmaxf(v, 0.f);
                C[(size_t)row * ldc + col] = f2bf(v);
            }
        }
    }
}

// ---------------------------------------------------------------------------
// SIMT tiled GEMM — final skinny projection (split-K atomic, verified).
// ---------------------------------------------------------------------------
__global__ __launch_bounds__(256) void k_gemm(
        const u16* __restrict__ A, int lda,
        const float* __restrict__ Bw, int ldb, size_t boff,
        float* __restrict__ C, int ldc, int kchunk)
{
    __shared__ float As[32][68];
    __shared__ float Bs[32][68];

    int tid = threadIdx.x;
    int tx = tid & 15, ty = tid >> 4;
    int m0 = blockIdx.x * 64;
    int n0 = blockIdx.y * 64;
    int k0 = blockIdx.z * kchunk;
    int kend = k0 + kchunk;

    int ar = tid >> 3;
    int ak = (tid & 7) << 2;

    float acc[4][4];
#pragma unroll
    for (int i = 0; i < 4; ++i)
#pragma unroll
        for (int j = 0; j < 4; ++j) acc[i][j] = 0.f;

    for (int k = k0; k < kend; k += 32) {
        __syncthreads();
#pragma unroll
        for (int pass = 0; pass < 2; ++pass) {
            int row = ar + pass * 32;
            ushort4 ua = *reinterpret_cast<const ushort4*>(
                &A[(size_t)(m0 + row) * lda + k + ak]);
            As[ak + 0][row] = u2f(ua.x); As[ak + 1][row] = u2f(ua.y);
            As[ak + 2][row] = u2f(ua.z); As[ak + 3][row] = u2f(ua.w);
            float4 vb = *reinterpret_cast<const float4*>(
                &Bw[boff + (size_t)(n0 + row) * ldb + k + ak]);
            Bs[ak + 0][row] = vb.x; Bs[ak + 1][row] = vb.y;
            Bs[ak + 2][row] = vb.z; Bs[ak + 3][row] = vb.w;
        }
        __syncthreads();
#pragma unroll
        for (int kk = 0; kk < 32; ++kk) {
            float4 av = *reinterpret_cast<const float4*>(&As[kk][ty << 2]);
            float4 bv = *reinterpret_cast<const float4*>(&Bs[kk][tx << 2]);
            float a4[4] = {av.x, av.y, av.z, av.w};
            float b4[4] = {bv.x, bv.y, bv.z, bv.w};
#pragma unroll
            for (int i = 0; i < 4; ++i)
#pragma unroll
                for (int j = 0; j < 4; ++j)
                    acc[i][j] += a4[i] * b4[j];
        }
    }

#pragma unroll
    for (int i = 0; i < 4; ++i) {
        int m = m0 + (ty << 2) + i;
#pragma unroll
        for (int j = 0; j < 4; ++j) {
            int n = n0 + (tx << 2) + j;
            atomicAdd(&C[(size_t)m * ldc + n], acc[i][j]);
        }
    }
}

// ---------------------------------------------------------------------------
// MFMA attention per (tree, head) — verified R12.
// ---------------------------------------------------------------------------
__global__ __launch_bounds__(256) void k_attn_mfma(u16* __restrict__ qkv)
{
    __shared__ __align__(16) u16 Ks[128 * 72];
    __shared__ __align__(16) u16 Vt[64 * 136];
    __shared__ __align__(16) u16 Ps[4][32 * 136];

    int blk = blockIdx.x;
    int t = blk >> 2, hd = blk & 3;
    int tid = threadIdx.x;
    int w = tid >> 6, lane = tid & 63;
    int ln15 = lane & 15, quad = lane >> 4;
    u16* base = qkv + (size_t)t * 128 * 768;

    for (int idx = tid; idx < 128 * 16; idx += 256) {
        int r = idx >> 4, d4 = (idx & 15) << 2;
        *reinterpret_cast<ushort4*>(&Ks[r * 72 + d4]) =
            *reinterpret_cast<const ushort4*>(&base[r * 768 + 256 + hd * 64 + d4]);
        ushort4 v = *reinterpret_cast<const ushort4*>(&base[r * 768 + 512 + hd * 64 + d4]);
        Vt[(d4 + 0) * 136 + r] = v.x;
        Vt[(d4 + 1) * 136 + r] = v.y;
        Vt[(d4 + 2) * 136 + r] = v.z;
        Vt[(d4 + 3) * 136 + r] = v.w;
    }

    bf16x8 qf[2][2];
#pragma unroll
    for (int i = 0; i < 2; ++i)
#pragma unroll
        for (int kk = 0; kk < 2; ++kk)
            qf[i][kk] = *reinterpret_cast<const bf16x8*>(
                &base[(size_t)(w * 32 + i * 16 + ln15) * 768 + hd * 64 + kk * 32 + quad * 8]);
    __syncthreads();

    f32x4 sa[2][8];
#pragma unroll
    for (int i = 0; i < 2; ++i)
#pragma unroll
        for (int j = 0; j < 8; ++j)
#pragma unroll
            for (int r = 0; r < 4; ++r) sa[i][j][r] = 0.f;

#pragma unroll
    for (int j = 0; j < 8; ++j)
#pragma unroll
        for (int kk = 0; kk < 2; ++kk) {
            bf16x8 kf = *reinterpret_cast<const bf16x8*>(
                &Ks[(j * 16 + ln15) * 72 + kk * 32 + quad * 8]);
            sa[0][j] = __builtin_amdgcn_mfma_f32_16x16x32_bf16(qf[0][kk], kf, sa[0][j], 0, 0, 0);
            sa[1][j] = __builtin_amdgcn_mfma_f32_16x16x32_bf16(qf[1][kk], kf, sa[1][j], 0, 0, 0);
        }

    const float scale = 0.125f;
#pragma unroll
    for (int i = 0; i < 2; ++i) {
#pragma unroll
        for (int r = 0; r < 4; ++r) {
            float m = -3e38f;
#pragma unroll
            for (int j = 0; j < 8; ++j) m = fmaxf(m, sa[i][j][r]);
            m = fmaxf(m, __shfl_xor(m, 1, 64));
            m = fmaxf(m, __shfl_xor(m, 2, 64));
            m = fmaxf(m, __shfl_xor(m, 4, 64));
            m = fmaxf(m, __shfl_xor(m, 8, 64));
            m *= scale;
            float p[8];
            float l = 0.f;
#pragma unroll
            for (int j = 0; j < 8; ++j) {
                p[j] = __expf(sa[i][j][r] * scale - m);
                l += p[j];
            }
            l += __shfl_xor(l, 1, 64);
            l += __shfl_xor(l, 2, 64);
            l += __shfl_xor(l, 4, 64);
            l += __shfl_xor(l, 8, 64);
            float inv = 1.f / l;
            int row = i * 16 + quad * 4 + r;
#pragma unroll
            for (int j = 0; j < 8; ++j)
                Ps[w][row * 136 + j * 16 + ln15] = f2bf(p[j] * inv);
        }
    }

    f32x4 oa[2][4];
#pragma unroll
    for (int i = 0; i < 2; ++i)
#pragma unroll
        for (int jt = 0; jt < 4; ++jt)
#pragma unroll
            for (int r = 0; r < 4; ++r) oa[i][jt][r] = 0.f;

#pragma unroll
    for (int ks = 0; ks < 4; ++ks) {
        bf16x8 pf0 = *reinterpret_cast<const bf16x8*>(
            &Ps[w][(0 + ln15) * 136 + ks * 32 + quad * 8]);
        bf16x8 pf1 = *reinterpret_cast<const bf16x8*>(
            &Ps[w][(16 + ln15) * 136 + ks * 32 + quad * 8]);
#pragma unroll
        for (int jt = 0; jt < 4; ++jt) {
            bf16x8 vf = *reinterpret_cast<const bf16x8*>(
                &Vt[(jt * 16 + ln15) * 136 + ks * 32 + quad * 8]);
            oa[0][jt] = __builtin_amdgcn_mfma_f32_16x16x32_bf16(pf0, vf, oa[0][jt], 0, 0, 0);
            oa[1][jt] = __builtin_amdgcn_mfma_f32_16x16x32_bf16(pf1, vf, oa[1][jt], 0, 0, 0);
        }
    }

#pragma unroll
    for (int i = 0; i < 2; ++i)
#pragma unroll
        for (int jt = 0; jt < 4; ++jt)
#pragma unroll
            for (int r = 0; r < 4; ++r) {
                int row = w * 32 + i * 16 + quad * 4 + r;
                int d = jt * 16 + ln15;
                base[(size_t)row * 768 + hd * 64 + d] = f2bf(oa[i][jt][r]);
            }
}

// ---------------------------------------------------------------------------
// x = LayerNorm(x + res) * w + b — wave-per-row, no LDS/barriers.
// block = 256 thr = 4 waves = 4 rows; lane handles 4 channels.
// ---------------------------------------------------------------------------
__global__ __launch_bounds__(256) void k_ln(
        u16* __restrict__ x, const u16* __restrict__ res, int rld,
        const float* __restrict__ w, const float* __restrict__ b, size_t woff)
{
    int row = blockIdx.x * 4 + (threadIdx.x >> 6);
    int lane = threadIdx.x & 63;
    u16* xr = x + (size_t)row * H_;
    const u16* rr = res + (size_t)row * rld;

    ushort4 xv = *reinterpret_cast<const ushort4*>(&xr[lane * 4]);
    ushort4 rv = *reinterpret_cast<const ushort4*>(&rr[lane * 4]);
    float v0 = u2f(xv.x) + u2f(rv.x);
    float v1 = u2f(xv.y) + u2f(rv.y);
    float v2 = u2f(xv.z) + u2f(rv.z);
    float v3 = u2f(xv.w) + u2f(rv.w);

    float s = v0 + v1 + v2 + v3;
#pragma unroll
    for (int o = 32; o > 0; o >>= 1) s += __shfl_xor(s, o, 64);
    float mu = s * (1.f / 256.f);
    float d0 = v0 - mu, d1 = v1 - mu, d2 = v2 - mu, d3 = v3 - mu;
    float s2 = d0 * d0 + d1 * d1 + d2 * d2 + d3 * d3;
#pragma unroll
    for (int o = 32; o > 0; o >>= 1) s2 += __shfl_xor(s2, o, 64);
    float rstd = rsqrtf(s2 * (1.f / 256.f) + 1e-5f);

    float4 wv = *reinterpret_cast<const float4*>(&w[woff + lane * 4]);
    float4 bv = *reinterpret_cast<const float4*>(&b[woff + lane * 4]);
    ushort4 ov;
    ov.x = f2bf(d0 * rstd * wv.x + bv.x);
    ov.y = f2bf(d1 * rstd * wv.y + bv.y);
    ov.z = f2bf(d2 * rstd * wv.z + bv.z);
    ov.w = f2bf(d3 * rstd * wv.w + bv.w);
    *reinterpret_cast<ushort4*>(&xr[lane * 4]) = ov;
}

// ---------------------------------------------------------------------------
__global__ __launch_bounds__(256) void k_zero(float* __restrict__ p, int n)
{
    int i = blockIdx.x * 256 + threadIdx.x;
    if (i < n) p[i] = 0.f;
}

// ---------------------------------------------------------------------------
// out = LayerNorm(Cf[row,:] + b_out) * lnf_w + lnf_b -> fp32 (verified R9)
// ---------------------------------------------------------------------------
__global__ __launch_bounds__(256) void k_lnf(
        const float* __restrict__ C, const float* __restrict__ b_out,
        const float* __restrict__ w, const float* __restrict__ b,
        float* __restrict__ out)
{
    int row = blockIdx.x * 256 + threadIdx.x;
    if (row >= T_) return;
    const float* cr = C + (size_t)row * OUT_;

    float s = 0.f;
    for (int o = 0; o < OUT_; ++o) s += cr[o] + b_out[o];
    float mu = s * (1.f / OUT_);
    float s2 = 0.f;
    for (int o = 0; o < OUT_; ++o) {
        float d = cr[o] + b_out[o] - mu;
        s2 += d * d;
    }
    float rstd = rsqrtf(s2 * (1.f / OUT_) + 1e-5f);
    for (int o = 0; o < OUT_; ++o) {
        float d = cr[o] + b_out[o] - mu;
        out[(size_t)row * OUT_ + o] = d * rstd * w[o] + b[o];
    }
}

// ---------------------------------------------------------------------------
extern "C" void kernel_launch(void* const* d_in, const int* in_sizes, int n_in,
                              void* d_out, int out_size, void* d_ws, size_t ws_size,
                              hipStream_t stream)
{
    static const int szA[23] = {
        1048576, 195072, 65536, 4096, 256, 98304, 256, 393216, 1536,
        131072, 512, 512, 512, 262144, 1024, 262144, 512, 512, 512,
        2097152, 64, 64, 64};
    static const int mapB[23] = {
        11, 3, 18, 0, 4, 2, 6, 22, 21, 20, 19, 13, 12, 8, 7, 10, 9,
        15, 14, 1, 5, 16, 17};
    bool isA = (n_in >= 23);
    for (int i = 0; i < 23 && i < n_in; ++i)
        if (in_sizes[i] != szA[i]) isA = false;
    const void* in[23];
    for (int i = 0; i < 23; ++i)
        in[i] = isA ? d_in[i] : d_in[mapB[i]];

    const float* forest = (const float*)in[0];
    const int*   adj    = (const int*)in[1];
    const int*   no     = (const int*)in[2];
    const float* W_in   = (const float*)in[3];
    const float* b_in   = (const float*)in[4];
    const float* W_pos  = (const float*)in[5];
    const float* b_pos  = (const float*)in[6];
    const float* qkv_w  = (const float*)in[7];
    const float* qkv_b  = (const float*)in[8];
    const float* outp_w = (const float*)in[9];
    const float* outp_b = (const float*)in[10];
    const float* ln1_w  = (const float*)in[11];
    const float* ln1_b  = (const float*)in[12];
    const float* ff1_w  = (const float*)in[13];
    const float* ff1_b  = (const float*)in[14];
    const float* ff2_w  = (const float*)in[15];
    const float* ff2_b  = (const float*)in[16];
    const float* ln2_w  = (const float*)in[17];
    const float* ln2_b  = (const float*)in[18];
    const float* W_out  = (const float*)in[19];
    const float* b_out  = (const float*)in[20];
    const float* lnf_w  = (const float*)in[21];
    const float* lnf_b  = (const float*)in[22];

    // ---- ws layout: mask | xb | wb (bf16) | init-prep f32 | cbuf ----
    int* mask = (int*)d_ws;                              // 256 KiB
    u16* xb   = (u16*)((char*)d_ws + (size_t)TOK_ * 4);  // 32 MiB
    u16* wb   = xb + (size_t)TOK_ * H_;                  // 2 MiB bf16 weights
    const size_t WB_QKV = 0;
    const size_t WB_OUT = 393216;
    const size_t WB_FF1 = 524288;
    const size_t WB_FF2 = 786432;
    float* prep  = (float*)(wb + 1048576);               // 33 KiB
    float* bsum  = prep;                                 // 256
    float* W_inT = prep + 256;                           // 4096
    float* W_posT= prep + 256 + 4096;                    // 4096 (p<16)
    u16* cbuf = (u16*)(prep + 256 + 4096 + 4096);        // rows x 768 bf16
    size_t used = (size_t)TOK_ * 4 + (size_t)TOK_ * H_ * 2 + 1048576 * 2
                + (256 + 4096 + 4096) * 4;
    size_t avail = (ws_size > used) ? ws_size - used : 0;
    size_t max_rows = avail / (768 * 2);
    int rc = (int)((max_rows / 128) * 128);
    if (rc > TOK_) rc = TOK_;
    if (rc < 128) rc = 128;

    // weight conversion fp32 -> bf16 + init-prep (per launch)
    k_cvt<<<512, 256, 0, stream>>>(qkv_w,  wb + WB_QKV, 393216);
    k_cvt<<<256, 256, 0, stream>>>(outp_w, wb + WB_OUT, 131072);
    k_cvt<<<512, 256, 0, stream>>>(ff1_w,  wb + WB_FF1, 262144);
    k_cvt<<<512, 256, 0, stream>>>(ff2_w,  wb + WB_FF2, 262144);
    k_prep<<<16, 256, 0, stream>>>(W_in, b_in, b_pos, W_pos,
                                   W_inT, W_posT, bsum);

    // pos bitmasks, then x0 (coalesced init)
    k_pos<<<(T_ + 255) / 256, 256, 0, stream>>>(adj, no, mask);
    k_init_x<<<TOK_ / 4, 256, 0, stream>>>(forest, mask, W_inT, W_posT,
                                           bsum, xb);

    // transformer layers, chunked over whole trees (MFMA GEMMs + MFMA attn)
    for (int R0 = 0; R0 < TOK_; R0 += rc) {
        int rows = (TOK_ - R0 < rc) ? (TOK_ - R0) : rc;   // multiple of 128
        u16* xc  = xb + (size_t)R0 * H_;
        u16* qc  = cbuf;                       // rows x 768
        u16* hc  = cbuf;                       // rows x 512 (reuse, qc dead)
        u16* h2c = cbuf + (size_t)rows * 512;  // rows x 256 (tail)

        for (int l = 0; l < L_; ++l) {
            // qkv = x @ qkv_w[l]^T + qkv_b[l]
            k_gemm_mfma<<<dim3(rows / 128, 768 / 128), 256, 0, stream>>>(
                xc, H_, wb + WB_QKV + (size_t)l * 768 * 256, 256,
                qkv_b, (size_t)l * 768, qc, 768, 256, 0);
            // attention in place (O over q slice) — MFMA flash
            k_attn_mfma<<<(rows / 128) * HEADS_, 256, 0, stream>>>(qc);
            // proj = O @ outp_w[l]^T + outp_b[l] -> cols 256..511
            k_gemm_mfma<<<dim3(rows / 128, 256 / 128), 256, 0, stream>>>(
                qc, 768, wb + WB_OUT + (size_t)l * 256 * 256, 256,
                outp_b, (size_t)l * 256, qc + 256, 768, 256, 0);
            // x = LN(x + proj)
            k_ln<<<rows / 4, 256, 0, stream>>>(xc, qc + 256, 768,
                                               ln1_w, ln1_b, (size_t)l * 256);
            // h = relu(x @ ff1_w[l]^T + ff1_b[l])
            k_gemm_mfma<<<dim3(rows / 128, 512 / 128), 256, 0, stream>>>(
                xc, H_, wb + WB_FF1 + (size_t)l * 512 * 256, 256,
                ff1_b, (size_t)l * 512, hc, 512, 256, 1);
            // h2 = h @ ff2_w[l]^T + ff2_b[l]
            k_gemm_mfma<<<dim3(rows / 128, 256 / 128), 256, 0, stream>>>(
                hc, 512, wb + WB_FF2 + (size_t)l * 256 * 512, 512,
                ff2_b, (size_t)l * 256, h2c, 256, 512, 0);
            // x = LN(x + h2)
            k_ln<<<rows / 4, 256, 0, stream>>>(xc, h2c, 256,
                                               ln2_w, ln2_b, (size_t)l * 256);
        }
    }

    // final: Cf = x.reshape(512, 32768) @ W_out^T (split-K=32, atomic fp32)
    float* Cf = (float*)cbuf;                  // 128 KiB, cbuf dead
    k_zero<<<(T_ * OUT_ + 255) / 256, 256, 0, stream>>>(Cf, T_ * OUT_);
    k_gemm<<<dim3(T_ / 64, OUT_ / 64, 32), 256, 0, stream>>>(
        xb, 32768, W_out, 32768, 0, Cf, OUT_, 1024);
    // out = LN(Cf + b_out) -> fp32
    k_lnf<<<(T_ + 255) / 256, 256, 0, stream>>>(Cf, b_out, lnf_w, lnf_b,
                                                (float*)d_out);
}

// Round 14
// 710.703 us; speedup vs baseline: 364.3293x; 1.1474x over previous
//
#include <hip/hip_runtime.h>

#define B_    128
#define A_    4
#define N_    128
#define F_IN_ 16
#define H_    256
#define HEADS_ 4
#define FF_   512
#define OUT_  64
#define BF_   3
#define L_    2
#define T_    512          // B*A
#define E_    127          // N-1
#define DH_   64
#define P_    384          // N*BF
#define TOK_  65536        // T*N

typedef unsigned short u16;
typedef __attribute__((ext_vector_type(8))) short bf16x8;   // 8 bf16 = 4 VGPR
typedef __attribute__((ext_vector_type(4))) float f32x4;

__device__ __forceinline__ float u2f(u16 u) {
    return __uint_as_float(((unsigned)u) << 16);
}
__device__ __forceinline__ u16 f2bf(float f) {
    unsigned u = __float_as_uint(f);
    unsigned r = (u + 0x7fffu + ((u >> 16) & 1u)) >> 16;
    return (u16)r;
}

// ---------------------------------------------------------------------------
// fp32 -> bf16 weight conversion (grid-stride)
// ---------------------------------------------------------------------------
__global__ __launch_bounds__(256) void k_cvt(
        const float* __restrict__ src, u16* __restrict__ dst, int n)
{
    for (int i = blockIdx.x * 256 + threadIdx.x; i < n; i += gridDim.x * 256)
        dst[i] = f2bf(src[i]);
}

// ---------------------------------------------------------------------------
// init-weight prep: W_inT[f][h] = W_in[h][f]; W_posT[p][h] = W_pos[h][p]
// (p < 16: only bits 0..14 reachable); bsum = b_in + b_pos.  grid 16 x 256.
// ---------------------------------------------------------------------------
__global__ __launch_bounds__(256) void k_prep(
        const float* __restrict__ W_in, const float* __restrict__ b_in,
        const float* __restrict__ b_pos, const float* __restrict__ W_pos,
        float* __restrict__ W_inT, float* __restrict__ W_posT,
        float* __restrict__ bsum)
{
    int i = blockIdx.x * 256 + threadIdx.x;
    if (i < 4096) W_inT[(i & 15) * 256 + (i >> 4)] = W_in[i];   // i = h*16+f
    if (i < 4096) {
        int p = i >> 8, h = i & 255;
        W_posT[i] = W_pos[(size_t)h * P_ + p];
    }
    if (i < 256) bsum[i] = b_in[i] + b_pos[i];
}

// ---------------------------------------------------------------------------
// pos bitmask, one thread per NODE via ancestor walk (HW-verified equivalent
// to the literal reference scan: R3-R5 walk outputs were bit-identical to
// R7-R8 literal-scan outputs). Node c's edge is adj row c-1; walk <=5 steps.
// bit for step i (bottom-up) = (nb-1-i)*3 + slot_idx.
// ---------------------------------------------------------------------------
__global__ __launch_bounds__(256) void k_pos(
        const int* __restrict__ adj, int* __restrict__ mask)
{
    int tn = blockIdx.x * 256 + threadIdx.x;
    if (tn >= TOK_) return;
    int t = tn >> 7;
    int n = tn & 127;

    int slots[8];
    int nb = 0;
    int c = n;
    while (c > 0 && nb < 8) {
        const int* e = adj + ((size_t)t * E_ + (c - 1)) * 3;
        int pg = e[0];
        int sl = e[2] + 1;
        sl = sl < 0 ? 0 : (sl > 2 ? 2 : sl);
        slots[nb++] = sl;
        c = pg - t * N_;
    }
    int mk = 0;
    for (int i = 0; i < nb; ++i)
        mk |= 1 << ((nb - 1 - i) * BF_ + slots[i]);
    mask[tn] = mk;
}

// ---------------------------------------------------------------------------
// x0 init, coalesced: block = 4 tokens x 256 channels; weights read once
// (coalesced via transposed copies) and reused for 4 tokens. (verified R13)
// ---------------------------------------------------------------------------
__global__ __launch_bounds__(256) void k_init_x(
        const float* __restrict__ forest, const int* __restrict__ mask,
        const float* __restrict__ W_inT, const float* __restrict__ W_posT,
        const float* __restrict__ bsum, u16* __restrict__ x)
{
    int h = threadIdx.x;
    int t0 = blockIdx.x * 4;

    float wf[16];
#pragma unroll
    for (int f = 0; f < F_IN_; ++f) wf[f] = W_inT[f * 256 + h];
    float bs = bsum[h];

#pragma unroll
    for (int tt = 0; tt < 4; ++tt) {
        int tn = t0 + tt;
        const float* fr = forest + (size_t)tn * F_IN_;
        float acc = bs;
#pragma unroll
        for (int f = 0; f < F_IN_; ++f) acc += fr[f] * wf[f];
        unsigned mk = (unsigned)mask[tn];
        while (mk) {
            int bit = __ffs(mk) - 1;
            mk &= mk - 1;
            acc += W_posT[bit * 256 + h];
        }
        x[(size_t)tn * H_ + h] = f2bf(acc);
    }
}

// ---------------------------------------------------------------------------
// MFMA GEMM (verified R11): C[m,n] = act(sum_k A[m,k]*Bw[n,k] + bias[..n])
// BM=BN=128, BK=32; 256 thr = 4 waves 2x2; wave = 4x4 tiles of 16x16.
// ---------------------------------------------------------------------------
__global__ __launch_bounds__(256) void k_gemm_mfma(
        const u16* __restrict__ A, int lda,
        const u16* __restrict__ Bw, int ldb,
        const float* __restrict__ bias, size_t biasoff,
        u16* __restrict__ C, int ldc,
        int K, int relu)
{
    __shared__ __align__(16) u16 As[128][40];
    __shared__ __align__(16) u16 Bs[128][40];

    int tid = threadIdx.x;
    int wid = tid >> 6, lane = tid & 63;
    int ln15 = lane & 15, quad = lane >> 4;
    int wm = (wid >> 1) * 64, wn = (wid & 1) * 64;
    size_t m0 = (size_t)blockIdx.x * 128;
    size_t n0 = (size_t)blockIdx.y * 128;

    f32x4 acc[4][4];
#pragma unroll
    for (int i = 0; i < 4; ++i)
#pragma unroll
        for (int j = 0; j < 4; ++j)
#pragma unroll
            for (int r = 0; r < 4; ++r) acc[i][j][r] = 0.f;

    for (int k0 = 0; k0 < K; k0 += 32) {
        __syncthreads();
#pragma unroll
        for (int s = 0; s < 2; ++s) {
            int idx = tid + s * 256;        // 0..511
            int r = idx >> 2;               // 0..127
            int kq = (idx & 3) * 8;         // 0,8,16,24
            *reinterpret_cast<uint4*>(&As[r][kq]) =
                *reinterpret_cast<const uint4*>(&A[(m0 + r) * (size_t)lda + k0 + kq]);
            *reinterpret_cast<uint4*>(&Bs[r][kq]) =
                *reinterpret_cast<const uint4*>(&Bw[(n0 + r) * (size_t)ldb + k0 + kq]);
        }
        __syncthreads();

        bf16x8 af[4], bfr[4];
#pragma unroll
        for (int i = 0; i < 4; ++i)
            af[i] = *reinterpret_cast<const bf16x8*>(&As[wm + i * 16 + ln15][quad * 8]);
#pragma unroll
        for (int j = 0; j < 4; ++j)
            bfr[j] = *reinterpret_cast<const bf16x8*>(&Bs[wn + j * 16 + ln15][quad * 8]);
#pragma unroll
        for (int i = 0; i < 4; ++i)
#pragma unroll
            for (int j = 0; j < 4; ++j)
                acc[i][j] = __builtin_amdgcn_mfma_f32_16x16x32_bf16(
                    af[i], bfr[j], acc[i][j], 0, 0, 0);
    }

#pragma unroll
    for (int i = 0; i < 4; ++i) {
#pragma unroll
        for (int j = 0; j < 4; ++j) {
            int col = (int)n0 + wn + j * 16 + ln15;
            float bv = bias ? bias[biasoff + col] : 0.f;
#pragma unroll
            for (int r = 0; r < 4; ++r) {
                int row = (int)m0 + wm + i * 16 + quad * 4 + r;
                float v = acc[i][j][r] + bv;
                if (relu) v = fmaxf(v, 0.f);
                C[(size_t)row * ldc + col] = f2bf(v);
            }
        }
    }
}

// ---------------------------------------------------------------------------
// SIMT tiled GEMM — final skinny projection (split-K atomic, verified).
// ---------------------------------------------------------------------------
__global__ __launch_bounds__(256) void k_gemm(
        const u16* __restrict__ A, int lda,
        const float* __restrict__ Bw, int ldb, size_t boff,
        float* __restrict__ C, int ldc, int kchunk)
{
    __shared__ float As[32][68];
    __shared__ float Bs[32][68];

    int tid = threadIdx.x;
    int tx = tid & 15, ty = tid >> 4;
    int m0 = blockIdx.x * 64;
    int n0 = blockIdx.y * 64;
    int k0 = blockIdx.z * kchunk;
    int kend = k0 + kchunk;

    int ar = tid >> 3;
    int ak = (tid & 7) << 2;

    float acc[4][4];
#pragma unroll
    for (int i = 0; i < 4; ++i)
#pragma unroll
        for (int j = 0; j < 4; ++j) acc[i][j] = 0.f;

    for (int k = k0; k < kend; k += 32) {
        __syncthreads();
#pragma unroll
        for (int pass = 0; pass < 2; ++pass) {
            int row = ar + pass * 32;
            ushort4 ua = *reinterpret_cast<const ushort4*>(
                &A[(size_t)(m0 + row) * lda + k + ak]);
            As[ak + 0][row] = u2f(ua.x); As[ak + 1][row] = u2f(ua.y);
            As[ak + 2][row] = u2f(ua.z); As[ak + 3][row] = u2f(ua.w);
            float4 vb = *reinterpret_cast<const float4*>(
                &Bw[boff + (size_t)(n0 + row) * ldb + k + ak]);
            Bs[ak + 0][row] = vb.x; Bs[ak + 1][row] = vb.y;
            Bs[ak + 2][row] = vb.z; Bs[ak + 3][row] = vb.w;
        }
        __syncthreads();
#pragma unroll
        for (int kk = 0; kk < 32; ++kk) {
            float4 av = *reinterpret_cast<const float4*>(&As[kk][ty << 2]);
            float4 bv = *reinterpret_cast<const float4*>(&Bs[kk][tx << 2]);
            float a4[4] = {av.x, av.y, av.z, av.w};
            float b4[4] = {bv.x, bv.y, bv.z, bv.w};
#pragma unroll
            for (int i = 0; i < 4; ++i)
#pragma unroll
                for (int j = 0; j < 4; ++j)
                    acc[i][j] += a4[i] * b4[j];
        }
    }

#pragma unroll
    for (int i = 0; i < 4; ++i) {
        int m = m0 + (ty << 2) + i;
#pragma unroll
        for (int j = 0; j < 4; ++j) {
            int n = n0 + (tx << 2) + j;
            atomicAdd(&C[(size_t)m * ldc + n], acc[i][j]);
        }
    }
}

// ---------------------------------------------------------------------------
// MFMA attention per (tree, head) — verified R12.
// ---------------------------------------------------------------------------
__global__ __launch_bounds__(256) void k_attn_mfma(u16* __restrict__ qkv)
{
    __shared__ __align__(16) u16 Ks[128 * 72];
    __shared__ __align__(16) u16 Vt[64 * 136];
    __shared__ __align__(16) u16 Ps[4][32 * 136];

    int blk = blockIdx.x;
    int t = blk >> 2, hd = blk & 3;
    int tid = threadIdx.x;
    int w = tid >> 6, lane = tid & 63;
    int ln15 = lane & 15, quad = lane >> 4;
    u16* base = qkv + (size_t)t * 128 * 768;

    for (int idx = tid; idx < 128 * 16; idx += 256) {
        int r = idx >> 4, d4 = (idx & 15) << 2;
        *reinterpret_cast<ushort4*>(&Ks[r * 72 + d4]) =
            *reinterpret_cast<const ushort4*>(&base[r * 768 + 256 + hd * 64 + d4]);
        ushort4 v = *reinterpret_cast<const ushort4*>(&base[r * 768 + 512 + hd * 64 + d4]);
        Vt[(d4 + 0) * 136 + r] = v.x;
        Vt[(d4 + 1) * 136 + r] = v.y;
        Vt[(d4 + 2) * 136 + r] = v.z;
        Vt[(d4 + 3) * 136 + r] = v.w;
    }

    bf16x8 qf[2][2];
#pragma unroll
    for (int i = 0; i < 2; ++i)
#pragma unroll
        for (int kk = 0; kk < 2; ++kk)
            qf[i][kk] = *reinterpret_cast<const bf16x8*>(
                &base[(size_t)(w * 32 + i * 16 + ln15) * 768 + hd * 64 + kk * 32 + quad * 8]);
    __syncthreads();

    f32x4 sa[2][8];
#pragma unroll
    for (int i = 0; i < 2; ++i)
#pragma unroll
        for (int j = 0; j < 8; ++j)
#pragma unroll
            for (int r = 0; r < 4; ++r) sa[i][j][r] = 0.f;

#pragma unroll
    for (int j = 0; j < 8; ++j)
#pragma unroll
        for (int kk = 0; kk < 2; ++kk) {
            bf16x8 kf = *reinterpret_cast<const bf16x8*>(
                &Ks[(j * 16 + ln15) * 72 + kk * 32 + quad * 8]);
            sa[0][j] = __builtin_amdgcn_mfma_f32_16x16x32_bf16(qf[0][kk], kf, sa[0][j], 0, 0, 0);
            sa[1][j] = __builtin_amdgcn_mfma_f32_16x16x32_bf16(qf[1][kk], kf, sa[1][j], 0, 0, 0);
        }

    const float scale = 0.125f;
#pragma unroll
    for (int i = 0; i < 2; ++i) {
#pragma unroll
        for (int r = 0; r < 4; ++r) {
            float m = -3e38f;
#pragma unroll
            for (int j = 0; j < 8; ++j) m = fmaxf(m, sa[i][j][r]);
            m = fmaxf(m, __shfl_xor(m, 1, 64));
            m = fmaxf(m, __shfl_xor(m, 2, 64));
            m = fmaxf(m, __shfl_xor(m, 4, 64));
            m = fmaxf(m, __shfl_xor(m, 8, 64));
            m *= scale;
            float p[8];
            float l = 0.f;
#pragma unroll
            for (int j = 0; j < 8; ++j) {
                p[j] = __expf(sa[i][j][r] * scale - m);
                l += p[j];
            }
            l += __shfl_xor(l, 1, 64);
            l += __shfl_xor(l, 2, 64);
            l += __shfl_xor(l, 4, 64);
            l += __shfl_xor(l, 8, 64);
            float inv = 1.f / l;
            int row = i * 16 + quad * 4 + r;
#pragma unroll
            for (int j = 0; j < 8; ++j)
                Ps[w][row * 136 + j * 16 + ln15] = f2bf(p[j] * inv);
        }
    }

    f32x4 oa[2][4];
#pragma unroll
    for (int i = 0; i < 2; ++i)
#pragma unroll
        for (int jt = 0; jt < 4; ++jt)
#pragma unroll
            for (int r = 0; r < 4; ++r) oa[i][jt][r] = 0.f;

#pragma unroll
    for (int ks = 0; ks < 4; ++ks) {
        bf16x8 pf0 = *reinterpret_cast<const bf16x8*>(
            &Ps[w][(0 + ln15) * 136 + ks * 32 + quad * 8]);
        bf16x8 pf1 = *reinterpret_cast<const bf16x8*>(
            &Ps[w][(16 + ln15) * 136 + ks * 32 + quad * 8]);
#pragma unroll
        for (int jt = 0; jt < 4; ++jt) {
            bf16x8 vf = *reinterpret_cast<const bf16x8*>(
                &Vt[(jt * 16 + ln15) * 136 + ks * 32 + quad * 8]);
            oa[0][jt] = __builtin_amdgcn_mfma_f32_16x16x32_bf16(pf0, vf, oa[0][jt], 0, 0, 0);
            oa[1][jt] = __builtin_amdgcn_mfma_f32_16x16x32_bf16(pf1, vf, oa[1][jt], 0, 0, 0);
        }
    }

#pragma unroll
    for (int i = 0; i < 2; ++i)
#pragma unroll
        for (int jt = 0; jt < 4; ++jt)
#pragma unroll
            for (int r = 0; r < 4; ++r) {
                int row = w * 32 + i * 16 + quad * 4 + r;
                int d = jt * 16 + ln15;
                base[(size_t)row * 768 + hd * 64 + d] = f2bf(oa[i][jt][r]);
            }
}

// ---------------------------------------------------------------------------
// x = LayerNorm(x + res) * w + b — wave-per-row (verified R13).
// ---------------------------------------------------------------------------
__global__ __launch_bounds__(256) void k_ln(
        u16* __restrict__ x, const u16* __restrict__ res, int rld,
        const float* __restrict__ w, const float* __restrict__ b, size_t woff)
{
    int row = blockIdx.x * 4 + (threadIdx.x >> 6);
    int lane = threadIdx.x & 63;
    u16* xr = x + (size_t)row * H_;
    const u16* rr = res + (size_t)row * rld;

    ushort4 xv = *reinterpret_cast<const ushort4*>(&xr[lane * 4]);
    ushort4 rv = *reinterpret_cast<const ushort4*>(&rr[lane * 4]);
    float v0 = u2f(xv.x) + u2f(rv.x);
    float v1 = u2f(xv.y) + u2f(rv.y);
    float v2 = u2f(xv.z) + u2f(rv.z);
    float v3 = u2f(xv.w) + u2f(rv.w);

    float s = v0 + v1 + v2 + v3;
#pragma unroll
    for (int o = 32; o > 0; o >>= 1) s += __shfl_xor(s, o, 64);
    float mu = s * (1.f / 256.f);
    float d0 = v0 - mu, d1 = v1 - mu, d2 = v2 - mu, d3 = v3 - mu;
    float s2 = d0 * d0 + d1 * d1 + d2 * d2 + d3 * d3;
#pragma unroll
    for (int o = 32; o > 0; o >>= 1) s2 += __shfl_xor(s2, o, 64);
    float rstd = rsqrtf(s2 * (1.f / 256.f) + 1e-5f);

    float4 wv = *reinterpret_cast<const float4*>(&w[woff + lane * 4]);
    float4 bv = *reinterpret_cast<const float4*>(&b[woff + lane * 4]);
    ushort4 ov;
    ov.x = f2bf(d0 * rstd * wv.x + bv.x);
    ov.y = f2bf(d1 * rstd * wv.y + bv.y);
    ov.z = f2bf(d2 * rstd * wv.z + bv.z);
    ov.w = f2bf(d3 * rstd * wv.w + bv.w);
    *reinterpret_cast<ushort4*>(&xr[lane * 4]) = ov;
}

// ---------------------------------------------------------------------------
__global__ __launch_bounds__(256) void k_zero(float* __restrict__ p, int n)
{
    int i = blockIdx.x * 256 + threadIdx.x;
    if (i < n) p[i] = 0.f;
}

// ---------------------------------------------------------------------------
// out = LayerNorm(Cf[row,:] + b_out) * lnf_w + lnf_b -> fp32 (verified R9)
// ---------------------------------------------------------------------------
__global__ __launch_bounds__(256) void k_lnf(
        const float* __restrict__ C, const float* __restrict__ b_out,
        const float* __restrict__ w, const float* __restrict__ b,
        float* __restrict__ out)
{
    int row = blockIdx.x * 256 + threadIdx.x;
    if (row >= T_) return;
    const float* cr = C + (size_t)row * OUT_;

    float s = 0.f;
    for (int o = 0; o < OUT_; ++o) s += cr[o] + b_out[o];
    float mu = s * (1.f / OUT_);
    float s2 = 0.f;
    for (int o = 0; o < OUT_; ++o) {
        float d = cr[o] + b_out[o] - mu;
        s2 += d * d;
    }
    float rstd = rsqrtf(s2 * (1.f / OUT_) + 1e-5f);
    for (int o = 0; o < OUT_; ++o) {
        float d = cr[o] + b_out[o] - mu;
        out[(size_t)row * OUT_ + o] = d * rstd * w[o] + b[o];
    }
}

// ---------------------------------------------------------------------------
extern "C" void kernel_launch(void* const* d_in, const int* in_sizes, int n_in,
                              void* d_out, int out_size, void* d_ws, size_t ws_size,
                              hipStream_t stream)
{
    static const int szA[23] = {
        1048576, 195072, 65536, 4096, 256, 98304, 256, 393216, 1536,
        131072, 512, 512, 512, 262144, 1024, 262144, 512, 512, 512,
        2097152, 64, 64, 64};
    static const int mapB[23] = {
        11, 3, 18, 0, 4, 2, 6, 22, 21, 20, 19, 13, 12, 8, 7, 10, 9,
        15, 14, 1, 5, 16, 17};
    bool isA = (n_in >= 23);
    for (int i = 0; i < 23 && i < n_in; ++i)
        if (in_sizes[i] != szA[i]) isA = false;
    const void* in[23];
    for (int i = 0; i < 23; ++i)
        in[i] = isA ? d_in[i] : d_in[mapB[i]];

    const float* forest = (const float*)in[0];
    const int*   adj    = (const int*)in[1];
    const float* W_in   = (const float*)in[3];
    const float* b_in   = (const float*)in[4];
    const float* W_pos  = (const float*)in[5];
    const float* b_pos  = (const float*)in[6];
    const float* qkv_w  = (const float*)in[7];
    const float* qkv_b  = (const float*)in[8];
    const float* outp_w = (const float*)in[9];
    const float* outp_b = (const float*)in[10];
    const float* ln1_w  = (const float*)in[11];
    const float* ln1_b  = (const float*)in[12];
    const float* ff1_w  = (const float*)in[13];
    const float* ff1_b  = (const float*)in[14];
    const float* ff2_w  = (const float*)in[15];
    const float* ff2_b  = (const float*)in[16];
    const float* ln2_w  = (const float*)in[17];
    const float* ln2_b  = (const float*)in[18];
    const float* W_out  = (const float*)in[19];
    const float* b_out  = (const float*)in[20];
    const float* lnf_w  = (const float*)in[21];
    const float* lnf_b  = (const float*)in[22];

    // ---- ws layout: mask | xb | wb (bf16) | init-prep f32 | cbuf ----
    int* mask = (int*)d_ws;                              // 256 KiB
    u16* xb   = (u16*)((char*)d_ws + (size_t)TOK_ * 4);  // 32 MiB
    u16* wb   = xb + (size_t)TOK_ * H_;                  // 2 MiB bf16 weights
    const size_t WB_QKV = 0;
    const size_t WB_OUT = 393216;
    const size_t WB_FF1 = 524288;
    const size_t WB_FF2 = 786432;
    float* prep  = (float*)(wb + 1048576);               // 33 KiB
    float* bsum  = prep;                                 // 256
    float* W_inT = prep + 256;                           // 4096
    float* W_posT= prep + 256 + 4096;                    // 4096 (p<16)
    u16* cbuf = (u16*)(prep + 256 + 4096 + 4096);        // rows x 768 bf16
    size_t used = (size_t)TOK_ * 4 + (size_t)TOK_ * H_ * 2 + 1048576 * 2
                + (256 + 4096 + 4096) * 4;
    size_t avail = (ws_size > used) ? ws_size - used : 0;
    size_t max_rows = avail / (768 * 2);
    int rc = (int)((max_rows / 128) * 128);
    if (rc > TOK_) rc = TOK_;
    if (rc < 128) rc = 128;

    // weight conversion fp32 -> bf16 + init-prep (per launch)
    k_cvt<<<512, 256, 0, stream>>>(qkv_w,  wb + WB_QKV, 393216);
    k_cvt<<<256, 256, 0, stream>>>(outp_w, wb + WB_OUT, 131072);
    k_cvt<<<512, 256, 0, stream>>>(ff1_w,  wb + WB_FF1, 262144);
    k_cvt<<<512, 256, 0, stream>>>(ff2_w,  wb + WB_FF2, 262144);
    k_prep<<<16, 256, 0, stream>>>(W_in, b_in, b_pos, W_pos,
                                   W_inT, W_posT, bsum);

    // pos bitmasks (per-node ancestor walk), then x0 (coalesced init)
    k_pos<<<TOK_ / 256, 256, 0, stream>>>(adj, mask);
    k_init_x<<<TOK_ / 4, 256, 0, stream>>>(forest, mask, W_inT, W_posT,
                                           bsum, xb);

    // transformer layers, chunked over whole trees (MFMA GEMMs + MFMA attn)
    for (int R0 = 0; R0 < TOK_; R0 += rc) {
        int rows = (TOK_ - R0 < rc) ? (TOK_ - R0) : rc;   // multiple of 128
        u16* xc  = xb + (size_t)R0 * H_;
        u16* qc  = cbuf;                       // rows x 768
        u16* hc  = cbuf;                       // rows x 512 (reuse, qc dead)
        u16* h2c = cbuf + (size_t)rows * 512;  // rows x 256 (tail)

        for (int l = 0; l < L_; ++l) {
            // qkv = x @ qkv_w[l]^T + qkv_b[l]
            k_gemm_mfma<<<dim3(rows / 128, 768 / 128), 256, 0, stream>>>(
                xc, H_, wb + WB_QKV + (size_t)l * 768 * 256, 256,
                qkv_b, (size_t)l * 768, qc, 768, 256, 0);
            // attention in place (O over q slice) — MFMA flash
            k_attn_mfma<<<(rows / 128) * HEADS_, 256, 0, stream>>>(qc);
            // proj = O @ outp_w[l]^T + outp_b[l] -> cols 256..511
            k_gemm_mfma<<<dim3(rows / 128, 256 / 128), 256, 0, stream>>>(
                qc, 768, wb + WB_OUT + (size_t)l * 256 * 256, 256,
                outp_b, (size_t)l * 256, qc + 256, 768, 256, 0);
            // x = LN(x + proj)
            k_ln<<<rows / 4, 256, 0, stream>>>(xc, qc + 256, 768,
                                               ln1_w, ln1_b, (size_t)l * 256);
            // h = relu(x @ ff1_w[l]^T + ff1_b[l])
            k_gemm_mfma<<<dim3(rows / 128, 512 / 128), 256, 0, stream>>>(
                xc, H_, wb + WB_FF1 + (size_t)l * 512 * 256, 256,
                ff1_b, (size_t)l * 512, hc, 512, 256, 1);
            // h2 = h @ ff2_w[l]^T + ff2_b[l]
            k_gemm_mfma<<<dim3(rows / 128, 256 / 128), 256, 0, stream>>>(
                hc, 512, wb + WB_FF2 + (size_t)l * 256 * 512, 512,
                ff2_b, (size_t)l * 256, h2c, 256, 512, 0);
            // x = LN(x + h2)
            k_ln<<<rows / 4, 256, 0, stream>>>(xc, h2c, 256,
                                               ln2_w, ln2_b, (size_t)l * 256);
        }
    }

    // final: Cf = x.reshape(512, 32768) @ W_out^T (split-K=32, atomic fp32)
    float* Cf = (float*)cbuf;                  // 128 KiB, cbuf dead
    k_zero<<<(T_ * OUT_ + 255) / 256, 256, 0, stream>>>(Cf, T_ * OUT_);
    k_gemm<<<dim3(T_ / 64, OUT_ / 64, 32), 256, 0, stream>>>(
        xb, 32768, W_out, 32768, 0, Cf, OUT_, 1024);
    // out = LN(Cf + b_out) -> fp32
    k_lnf<<<(T_ + 255) / 256, 256, 0, stream>>>(Cf, b_out, lnf_w, lnf_b,
                                                (float*)d_out);
}

// Round 15
// 702.044 us; speedup vs baseline: 368.8228x; 1.0123x over previous
//
#include <hip/hip_runtime.h>

#define B_    128
#define A_    4
#define N_    128
#define F_IN_ 16
#define H_    256
#define HEADS_ 4
#define FF_   512
#define OUT_  64
#define BF_   3
#define L_    2
#define T_    512          // B*A
#define E_    127          // N-1
#define DH_   64
#define P_    384          // N*BF
#define TOK_  65536        // T*N

typedef unsigned short u16;
typedef __attribute__((ext_vector_type(8))) short bf16x8;   // 8 bf16 = 4 VGPR
typedef __attribute__((ext_vector_type(4))) float f32x4;

__device__ __forceinline__ float u2f(u16 u) {
    return __uint_as_float(((unsigned)u) << 16);
}
__device__ __forceinline__ u16 f2bf(float f) {
    unsigned u = __float_as_uint(f);
    unsigned r = (u + 0x7fffu + ((u >> 16) & 1u)) >> 16;
    return (u16)r;
}

// ---------------------------------------------------------------------------
// fp32 -> bf16 weight conversion (grid-stride)
// ---------------------------------------------------------------------------
__global__ __launch_bounds__(256) void k_cvt(
        const float* __restrict__ src, u16* __restrict__ dst, int n)
{
    for (int i = blockIdx.x * 256 + threadIdx.x; i < n; i += gridDim.x * 256)
        dst[i] = f2bf(src[i]);
}

// ---------------------------------------------------------------------------
// init-weight prep: W_inT[f][h] = W_in[h][f]; W_posT[p][h] = W_pos[h][p]
// (p < 16: only bits 0..14 reachable); bsum = b_in + b_pos.  grid 16 x 256.
// ---------------------------------------------------------------------------
__global__ __launch_bounds__(256) void k_prep(
        const float* __restrict__ W_in, const float* __restrict__ b_in,
        const float* __restrict__ b_pos, const float* __restrict__ W_pos,
        float* __restrict__ W_inT, float* __restrict__ W_posT,
        float* __restrict__ bsum)
{
    int i = blockIdx.x * 256 + threadIdx.x;
    if (i < 4096) W_inT[(i & 15) * 256 + (i >> 4)] = W_in[i];   // i = h*16+f
    if (i < 4096) {
        int p = i >> 8, h = i & 255;
        W_posT[i] = W_pos[(size_t)h * P_ + p];
    }
    if (i < 256) bsum[i] = b_in[i] + b_pos[i];
}

// ---------------------------------------------------------------------------
// pos bitmask, one thread per NODE via ancestor walk (verified R14; walk is
// HW-verified bit-identical to the literal reference scan).
// ---------------------------------------------------------------------------
__global__ __launch_bounds__(256) void k_pos(
        const int* __restrict__ adj, int* __restrict__ mask)
{
    int tn = blockIdx.x * 256 + threadIdx.x;
    if (tn >= TOK_) return;
    int t = tn >> 7;
    int n = tn & 127;

    int slots[8];
    int nb = 0;
    int c = n;
    while (c > 0 && nb < 8) {
        const int* e = adj + ((size_t)t * E_ + (c - 1)) * 3;
        int pg = e[0];
        int sl = e[2] + 1;
        sl = sl < 0 ? 0 : (sl > 2 ? 2 : sl);
        slots[nb++] = sl;
        c = pg - t * N_;
    }
    int mk = 0;
    for (int i = 0; i < nb; ++i)
        mk |= 1 << ((nb - 1 - i) * BF_ + slots[i]);
    mask[tn] = mk;
}

// ---------------------------------------------------------------------------
// x0 init, coalesced (verified R13): block = 4 tokens x 256 channels.
// ---------------------------------------------------------------------------
__global__ __launch_bounds__(256) void k_init_x(
        const float* __restrict__ forest, const int* __restrict__ mask,
        const float* __restrict__ W_inT, const float* __restrict__ W_posT,
        const float* __restrict__ bsum, u16* __restrict__ x)
{
    int h = threadIdx.x;
    int t0 = blockIdx.x * 4;

    float wf[16];
#pragma unroll
    for (int f = 0; f < F_IN_; ++f) wf[f] = W_inT[f * 256 + h];
    float bs = bsum[h];

#pragma unroll
    for (int tt = 0; tt < 4; ++tt) {
        int tn = t0 + tt;
        const float* fr = forest + (size_t)tn * F_IN_;
        float acc = bs;
#pragma unroll
        for (int f = 0; f < F_IN_; ++f) acc += fr[f] * wf[f];
        unsigned mk = (unsigned)mask[tn];
        while (mk) {
            int bit = __ffs(mk) - 1;
            mk &= mk - 1;
            acc += W_posT[bit * 256 + h];
        }
        x[(size_t)tn * H_ + h] = f2bf(acc);
    }
}

// ---------------------------------------------------------------------------
// MFMA GEMM (verified R11): C[m,n] = act(sum_k A[m,k]*Bw[n,k] + bias[..n])
// BM=BN=128, BK=32; 256 thr = 4 waves 2x2; wave = 4x4 tiles of 16x16.
// ---------------------------------------------------------------------------
__global__ __launch_bounds__(256) void k_gemm_mfma(
        const u16* __restrict__ A, int lda,
        const u16* __restrict__ Bw, int ldb,
        const float* __restrict__ bias, size_t biasoff,
        u16* __restrict__ C, int ldc,
        int K, int relu)
{
    __shared__ __align__(16) u16 As[128][40];
    __shared__ __align__(16) u16 Bs[128][40];

    int tid = threadIdx.x;
    int wid = tid >> 6, lane = tid & 63;
    int ln15 = lane & 15, quad = lane >> 4;
    int wm = (wid >> 1) * 64, wn = (wid & 1) * 64;
    size_t m0 = (size_t)blockIdx.x * 128;
    size_t n0 = (size_t)blockIdx.y * 128;

    f32x4 acc[4][4];
#pragma unroll
    for (int i = 0; i < 4; ++i)
#pragma unroll
        for (int j = 0; j < 4; ++j)
#pragma unroll
            for (int r = 0; r < 4; ++r) acc[i][j][r] = 0.f;

    for (int k0 = 0; k0 < K; k0 += 32) {
        __syncthreads();
#pragma unroll
        for (int s = 0; s < 2; ++s) {
            int idx = tid + s * 256;        // 0..511
            int r = idx >> 2;               // 0..127
            int kq = (idx & 3) * 8;         // 0,8,16,24
            *reinterpret_cast<uint4*>(&As[r][kq]) =
                *reinterpret_cast<const uint4*>(&A[(m0 + r) * (size_t)lda + k0 + kq]);
            *reinterpret_cast<uint4*>(&Bs[r][kq]) =
                *reinterpret_cast<const uint4*>(&Bw[(n0 + r) * (size_t)ldb + k0 + kq]);
        }
        __syncthreads();

        bf16x8 af[4], bfr[4];
#pragma unroll
        for (int i = 0; i < 4; ++i)
            af[i] = *reinterpret_cast<const bf16x8*>(&As[wm + i * 16 + ln15][quad * 8]);
#pragma unroll
        for (int j = 0; j < 4; ++j)
            bfr[j] = *reinterpret_cast<const bf16x8*>(&Bs[wn + j * 16 + ln15][quad * 8]);
#pragma unroll
        for (int i = 0; i < 4; ++i)
#pragma unroll
            for (int j = 0; j < 4; ++j)
                acc[i][j] = __builtin_amdgcn_mfma_f32_16x16x32_bf16(
                    af[i], bfr[j], acc[i][j], 0, 0, 0);
    }

#pragma unroll
    for (int i = 0; i < 4; ++i) {
#pragma unroll
        for (int j = 0; j < 4; ++j) {
            int col = (int)n0 + wn + j * 16 + ln15;
            float bv = bias ? bias[biasoff + col] : 0.f;
#pragma unroll
            for (int r = 0; r < 4; ++r) {
                int row = (int)m0 + wm + i * 16 + quad * 4 + r;
                float v = acc[i][j][r] + bv;
                if (relu) v = fmaxf(v, 0.f);
                C[(size_t)row * ldc + col] = f2bf(v);
            }
        }
    }
}

// ---------------------------------------------------------------------------
// MFMA final projection: Cf[512][64] += A[512][32768] @ Bw[64][32768]^T
// grid (M/64=8, KSPLIT=32) = 256 blocks (1/CU); 4 waves; wave = 16x64 strip.
// BK=64; fp32 atomicAdd epilogue (Cf pre-zeroed). Fragments as k_gemm_mfma.
// ---------------------------------------------------------------------------
__global__ __launch_bounds__(256) void k_gemm_fin(
        const u16* __restrict__ A, const u16* __restrict__ Bw,
        float* __restrict__ C, int kchunk)
{
    __shared__ __align__(16) u16 As[64][72];
    __shared__ __align__(16) u16 Bs[64][72];

    int tid = threadIdx.x;
    int w = tid >> 6, lane = tid & 63;
    int ln15 = lane & 15, quad = lane >> 4;
    size_t m0 = (size_t)blockIdx.x * 64;
    int k0 = blockIdx.y * kchunk;

    f32x4 acc[4];
#pragma unroll
    for (int j = 0; j < 4; ++j)
#pragma unroll
        for (int r = 0; r < 4; ++r) acc[j][r] = 0.f;

    for (int kk = k0; kk < k0 + kchunk; kk += 64) {
        __syncthreads();
#pragma unroll
        for (int s = 0; s < 2; ++s) {
            int idx = tid + s * 256;        // 0..511
            int r = idx >> 3;               // 0..63
            int c8 = (idx & 7) * 8;         // 0,8,...,56
            *reinterpret_cast<uint4*>(&As[r][c8]) =
                *reinterpret_cast<const uint4*>(&A[(m0 + r) * 32768 + kk + c8]);
            *reinterpret_cast<uint4*>(&Bs[r][c8]) =
                *reinterpret_cast<const uint4*>(&Bw[(size_t)r * 32768 + kk + c8]);
        }
        __syncthreads();

        bf16x8 af[2];
#pragma unroll
        for (int kh = 0; kh < 2; ++kh)
            af[kh] = *reinterpret_cast<const bf16x8*>(
                &As[w * 16 + ln15][kh * 32 + quad * 8]);
#pragma unroll
        for (int j = 0; j < 4; ++j)
#pragma unroll
            for (int kh = 0; kh < 2; ++kh) {
                bf16x8 bf = *reinterpret_cast<const bf16x8*>(
                    &Bs[j * 16 + ln15][kh * 32 + quad * 8]);
                acc[j] = __builtin_amdgcn_mfma_f32_16x16x32_bf16(
                    af[kh], bf, acc[j], 0, 0, 0);
            }
    }

#pragma unroll
    for (int j = 0; j < 4; ++j)
#pragma unroll
        for (int r = 0; r < 4; ++r) {
            int row = (int)m0 + w * 16 + quad * 4 + r;
            int col = j * 16 + ln15;
            atomicAdd(&C[(size_t)row * OUT_ + col], acc[j][r]);
        }
}

// ---------------------------------------------------------------------------
// MFMA attention per (tree, head) — verified R12.
// ---------------------------------------------------------------------------
__global__ __launch_bounds__(256) void k_attn_mfma(u16* __restrict__ qkv)
{
    __shared__ __align__(16) u16 Ks[128 * 72];
    __shared__ __align__(16) u16 Vt[64 * 136];
    __shared__ __align__(16) u16 Ps[4][32 * 136];

    int blk = blockIdx.x;
    int t = blk >> 2, hd = blk & 3;
    int tid = threadIdx.x;
    int w = tid >> 6, lane = tid & 63;
    int ln15 = lane & 15, quad = lane >> 4;
    u16* base = qkv + (size_t)t * 128 * 768;

    for (int idx = tid; idx < 128 * 16; idx += 256) {
        int r = idx >> 4, d4 = (idx & 15) << 2;
        *reinterpret_cast<ushort4*>(&Ks[r * 72 + d4]) =
            *reinterpret_cast<const ushort4*>(&base[r * 768 + 256 + hd * 64 + d4]);
        ushort4 v = *reinterpret_cast<const ushort4*>(&base[r * 768 + 512 + hd * 64 + d4]);
        Vt[(d4 + 0) * 136 + r] = v.x;
        Vt[(d4 + 1) * 136 + r] = v.y;
        Vt[(d4 + 2) * 136 + r] = v.z;
        Vt[(d4 + 3) * 136 + r] = v.w;
    }

    bf16x8 qf[2][2];
#pragma unroll
    for (int i = 0; i < 2; ++i)
#pragma unroll
        for (int kk = 0; kk < 2; ++kk)
            qf[i][kk] = *reinterpret_cast<const bf16x8*>(
                &base[(size_t)(w * 32 + i * 16 + ln15) * 768 + hd * 64 + kk * 32 + quad * 8]);
    __syncthreads();

    f32x4 sa[2][8];
#pragma unroll
    for (int i = 0; i < 2; ++i)
#pragma unroll
        for (int j = 0; j < 8; ++j)
#pragma unroll
            for (int r = 0; r < 4; ++r) sa[i][j][r] = 0.f;

#pragma unroll
    for (int j = 0; j < 8; ++j)
#pragma unroll
        for (int kk = 0; kk < 2; ++kk) {
            bf16x8 kf = *reinterpret_cast<const bf16x8*>(
                &Ks[(j * 16 + ln15) * 72 + kk * 32 + quad * 8]);
            sa[0][j] = __builtin_amdgcn_mfma_f32_16x16x32_bf16(qf[0][kk], kf, sa[0][j], 0, 0, 0);
            sa[1][j] = __builtin_amdgcn_mfma_f32_16x16x32_bf16(qf[1][kk], kf, sa[1][j], 0, 0, 0);
        }

    const float scale = 0.125f;
#pragma unroll
    for (int i = 0; i < 2; ++i) {
#pragma unroll
        for (int r = 0; r < 4; ++r) {
            float m = -3e38f;
#pragma unroll
            for (int j = 0; j < 8; ++j) m = fmaxf(m, sa[i][j][r]);
            m = fmaxf(m, __shfl_xor(m, 1, 64));
            m = fmaxf(m, __shfl_xor(m, 2, 64));
            m = fmaxf(m, __shfl_xor(m, 4, 64));
            m = fmaxf(m, __shfl_xor(m, 8, 64));
            m *= scale;
            float p[8];
            float l = 0.f;
#pragma unroll
            for (int j = 0; j < 8; ++j) {
                p[j] = __expf(sa[i][j][r] * scale - m);
                l += p[j];
            }
            l += __shfl_xor(l, 1, 64);
            l += __shfl_xor(l, 2, 64);
            l += __shfl_xor(l, 4, 64);
            l += __shfl_xor(l, 8, 64);
            float inv = 1.f / l;
            int row = i * 16 + quad * 4 + r;
#pragma unroll
            for (int j = 0; j < 8; ++j)
                Ps[w][row * 136 + j * 16 + ln15] = f2bf(p[j] * inv);
        }
    }

    f32x4 oa[2][4];
#pragma unroll
    for (int i = 0; i < 2; ++i)
#pragma unroll
        for (int jt = 0; jt < 4; ++jt)
#pragma unroll
            for (int r = 0; r < 4; ++r) oa[i][jt][r] = 0.f;

#pragma unroll
    for (int ks = 0; ks < 4; ++ks) {
        bf16x8 pf0 = *reinterpret_cast<const bf16x8*>(
            &Ps[w][(0 + ln15) * 136 + ks * 32 + quad * 8]);
        bf16x8 pf1 = *reinterpret_cast<const bf16x8*>(
            &Ps[w][(16 + ln15) * 136 + ks * 32 + quad * 8]);
#pragma unroll
        for (int jt = 0; jt < 4; ++jt) {
            bf16x8 vf = *reinterpret_cast<const bf16x8*>(
                &Vt[(jt * 16 + ln15) * 136 + ks * 32 + quad * 8]);
            oa[0][jt] = __builtin_amdgcn_mfma_f32_16x16x32_bf16(pf0, vf, oa[0][jt], 0, 0, 0);
            oa[1][jt] = __builtin_amdgcn_mfma_f32_16x16x32_bf16(pf1, vf, oa[1][jt], 0, 0, 0);
        }
    }

#pragma unroll
    for (int i = 0; i < 2; ++i)
#pragma unroll
        for (int jt = 0; jt < 4; ++jt)
#pragma unroll
            for (int r = 0; r < 4; ++r) {
                int row = w * 32 + i * 16 + quad * 4 + r;
                int d = jt * 16 + ln15;
                base[(size_t)row * 768 + hd * 64 + d] = f2bf(oa[i][jt][r]);
            }
}

// ---------------------------------------------------------------------------
// x = LayerNorm(x + res) * w + b — wave-per-row (verified R13).
// ---------------------------------------------------------------------------
__global__ __launch_bounds__(256) void k_ln(
        u16* __restrict__ x, const u16* __restrict__ res, int rld,
        const float* __restrict__ w, const float* __restrict__ b, size_t woff)
{
    int row = blockIdx.x * 4 + (threadIdx.x >> 6);
    int lane = threadIdx.x & 63;
    u16* xr = x + (size_t)row * H_;
    const u16* rr = res + (size_t)row * rld;

    ushort4 xv = *reinterpret_cast<const ushort4*>(&xr[lane * 4]);
    ushort4 rv = *reinterpret_cast<const ushort4*>(&rr[lane * 4]);
    float v0 = u2f(xv.x) + u2f(rv.x);
    float v1 = u2f(xv.y) + u2f(rv.y);
    float v2 = u2f(xv.z) + u2f(rv.z);
    float v3 = u2f(xv.w) + u2f(rv.w);

    float s = v0 + v1 + v2 + v3;
#pragma unroll
    for (int o = 32; o > 0; o >>= 1) s += __shfl_xor(s, o, 64);
    float mu = s * (1.f / 256.f);
    float d0 = v0 - mu, d1 = v1 - mu, d2 = v2 - mu, d3 = v3 - mu;
    float s2 = d0 * d0 + d1 * d1 + d2 * d2 + d3 * d3;
#pragma unroll
    for (int o = 32; o > 0; o >>= 1) s2 += __shfl_xor(s2, o, 64);
    float rstd = rsqrtf(s2 * (1.f / 256.f) + 1e-5f);

    float4 wv = *reinterpret_cast<const float4*>(&w[woff + lane * 4]);
    float4 bv = *reinterpret_cast<const float4*>(&b[woff + lane * 4]);
    ushort4 ov;
    ov.x = f2bf(d0 * rstd * wv.x + bv.x);
    ov.y = f2bf(d1 * rstd * wv.y + bv.y);
    ov.z = f2bf(d2 * rstd * wv.z + bv.z);
    ov.w = f2bf(d3 * rstd * wv.w + bv.w);
    *reinterpret_cast<ushort4*>(&xr[lane * 4]) = ov;
}

// ---------------------------------------------------------------------------
__global__ __launch_bounds__(256) void k_zero(float* __restrict__ p, int n)
{
    int i = blockIdx.x * 256 + threadIdx.x;
    if (i < n) p[i] = 0.f;
}

// ---------------------------------------------------------------------------
// out = LayerNorm(Cf[row,:] + b_out) * lnf_w + lnf_b -> fp32 (verified R9)
// ---------------------------------------------------------------------------
__global__ __launch_bounds__(256) void k_lnf(
        const float* __restrict__ C, const float* __restrict__ b_out,
        const float* __restrict__ w, const float* __restrict__ b,
        float* __restrict__ out)
{
    int row = blockIdx.x * 256 + threadIdx.x;
    if (row >= T_) return;
    const float* cr = C + (size_t)row * OUT_;

    float s = 0.f;
    for (int o = 0; o < OUT_; ++o) s += cr[o] + b_out[o];
    float mu = s * (1.f / OUT_);
    float s2 = 0.f;
    for (int o = 0; o < OUT_; ++o) {
        float d = cr[o] + b_out[o] - mu;
        s2 += d * d;
    }
    float rstd = rsqrtf(s2 * (1.f / OUT_) + 1e-5f);
    for (int o = 0; o < OUT_; ++o) {
        float d = cr[o] + b_out[o] - mu;
        out[(size_t)row * OUT_ + o] = d * rstd * w[o] + b[o];
    }
}

// ---------------------------------------------------------------------------
extern "C" void kernel_launch(void* const* d_in, const int* in_sizes, int n_in,
                              void* d_out, int out_size, void* d_ws, size_t ws_size,
                              hipStream_t stream)
{
    static const int szA[23] = {
        1048576, 195072, 65536, 4096, 256, 98304, 256, 393216, 1536,
        131072, 512, 512, 512, 262144, 1024, 262144, 512, 512, 512,
        2097152, 64, 64, 64};
    static const int mapB[23] = {
        11, 3, 18, 0, 4, 2, 6, 22, 21, 20, 19, 13, 12, 8, 7, 10, 9,
        15, 14, 1, 5, 16, 17};
    bool isA = (n_in >= 23);
    for (int i = 0; i < 23 && i < n_in; ++i)
        if (in_sizes[i] != szA[i]) isA = false;
    const void* in[23];
    for (int i = 0; i < 23; ++i)
        in[i] = isA ? d_in[i] : d_in[mapB[i]];

    const float* forest = (const float*)in[0];
    const int*   adj    = (const int*)in[1];
    const float* W_in   = (const float*)in[3];
    const float* b_in   = (const float*)in[4];
    const float* W_pos  = (const float*)in[5];
    const float* b_pos  = (const float*)in[6];
    const float* qkv_w  = (const float*)in[7];
    const float* qkv_b  = (const float*)in[8];
    const float* outp_w = (const float*)in[9];
    const float* outp_b = (const float*)in[10];
    const float* ln1_w  = (const float*)in[11];
    const float* ln1_b  = (const float*)in[12];
    const float* ff1_w  = (const float*)in[13];
    const float* ff1_b  = (const float*)in[14];
    const float* ff2_w  = (const float*)in[15];
    const float* ff2_b  = (const float*)in[16];
    const float* ln2_w  = (const float*)in[17];
    const float* ln2_b  = (const float*)in[18];
    const float* W_out  = (const float*)in[19];
    const float* b_out  = (const float*)in[20];
    const float* lnf_w  = (const float*)in[21];
    const float* lnf_b  = (const float*)in[22];

    // ---- ws layout: mask | xb | wb (bf16, incl W_out) | prep f32 | cbuf ----
    int* mask = (int*)d_ws;                              // 256 KiB
    u16* xb   = (u16*)((char*)d_ws + (size_t)TOK_ * 4);  // 32 MiB
    u16* wb   = xb + (size_t)TOK_ * H_;                  // 6 MiB bf16 weights
    const size_t WB_QKV  = 0;
    const size_t WB_OUT  = 393216;
    const size_t WB_FF1  = 524288;
    const size_t WB_FF2  = 786432;
    const size_t WB_WOUT = 1048576;                      // 2097152 u16
    const size_t WB_TOT  = 1048576 + 2097152;            // 3145728 u16
    float* prep  = (float*)(wb + WB_TOT);                // 33 KiB
    float* bsum  = prep;                                 // 256
    float* W_inT = prep + 256;                           // 4096
    float* W_posT= prep + 256 + 4096;                    // 4096 (p<16)
    u16* cbuf = (u16*)(prep + 256 + 4096 + 4096);        // rows x 768 bf16
    size_t used = (size_t)TOK_ * 4 + (size_t)TOK_ * H_ * 2 + WB_TOT * 2
                + (256 + 4096 + 4096) * 4;
    size_t avail = (ws_size > used) ? ws_size - used : 0;
    size_t max_rows = avail / (768 * 2);
    int rc = (int)((max_rows / 128) * 128);
    if (rc > TOK_) rc = TOK_;
    if (rc < 128) rc = 128;

    // weight conversion fp32 -> bf16 + init-prep (per launch)
    k_cvt<<<512, 256, 0, stream>>>(qkv_w,  wb + WB_QKV, 393216);
    k_cvt<<<256, 256, 0, stream>>>(outp_w, wb + WB_OUT, 131072);
    k_cvt<<<512, 256, 0, stream>>>(ff1_w,  wb + WB_FF1, 262144);
    k_cvt<<<512, 256, 0, stream>>>(ff2_w,  wb + WB_FF2, 262144);
    k_cvt<<<1024, 256, 0, stream>>>(W_out, wb + WB_WOUT, 2097152);
    k_prep<<<16, 256, 0, stream>>>(W_in, b_in, b_pos, W_pos,
                                   W_inT, W_posT, bsum);

    // pos bitmasks (per-node ancestor walk), then x0 (coalesced init)
    k_pos<<<TOK_ / 256, 256, 0, stream>>>(adj, mask);
    k_init_x<<<TOK_ / 4, 256, 0, stream>>>(forest, mask, W_inT, W_posT,
                                           bsum, xb);

    // transformer layers, chunked over whole trees (MFMA GEMMs + MFMA attn)
    for (int R0 = 0; R0 < TOK_; R0 += rc) {
        int rows = (TOK_ - R0 < rc) ? (TOK_ - R0) : rc;   // multiple of 128
        u16* xc  = xb + (size_t)R0 * H_;
        u16* qc  = cbuf;                       // rows x 768
        u16* hc  = cbuf;                       // rows x 512 (reuse, qc dead)
        u16* h2c = cbuf + (size_t)rows * 512;  // rows x 256 (tail)

        for (int l = 0; l < L_; ++l) {
            // qkv = x @ qkv_w[l]^T + qkv_b[l]
            k_gemm_mfma<<<dim3(rows / 128, 768 / 128), 256, 0, stream>>>(
                xc, H_, wb + WB_QKV + (size_t)l * 768 * 256, 256,
                qkv_b, (size_t)l * 768, qc, 768, 256, 0);
            // attention in place (O over q slice) — MFMA flash
            k_attn_mfma<<<(rows / 128) * HEADS_, 256, 0, stream>>>(qc);
            // proj = O @ outp_w[l]^T + outp_b[l] -> cols 256..511
            k_gemm_mfma<<<dim3(rows / 128, 256 / 128), 256, 0, stream>>>(
                qc, 768, wb + WB_OUT + (size_t)l * 256 * 256, 256,
                outp_b, (size_t)l * 256, qc + 256, 768, 256, 0);
            // x = LN(x + proj)
            k_ln<<<rows / 4, 256, 0, stream>>>(xc, qc + 256, 768,
                                               ln1_w, ln1_b, (size_t)l * 256);
            // h = relu(x @ ff1_w[l]^T + ff1_b[l])
            k_gemm_mfma<<<dim3(rows / 128, 512 / 128), 256, 0, stream>>>(
                xc, H_, wb + WB_FF1 + (size_t)l * 512 * 256, 256,
                ff1_b, (size_t)l * 512, hc, 512, 256, 1);
            // h2 = h @ ff2_w[l]^T + ff2_b[l]
            k_gemm_mfma<<<dim3(rows / 128, 256 / 128), 256, 0, stream>>>(
                hc, 512, wb + WB_FF2 + (size_t)l * 256 * 512, 512,
                ff2_b, (size_t)l * 256, h2c, 256, 512, 0);
            // x = LN(x + h2)
            k_ln<<<rows / 4, 256, 0, stream>>>(xc, h2c, 256,
                                               ln2_w, ln2_b, (size_t)l * 256);
        }
    }

    // final: Cf = x.reshape(512, 32768) @ W_out^T (MFMA, split-K=32, atomic)
    float* Cf = (float*)cbuf;                  // 128 KiB, cbuf dead
    k_zero<<<(T_ * OUT_ + 255) / 256, 256, 0, stream>>>(Cf, T_ * OUT_);
    k_gemm_fin<<<dim3(T_ / 64, 32), 256, 0, stream>>>(
        xb, wb + WB_WOUT, Cf, 1024);
    // out = LN(Cf + b_out) -> fp32
    k_lnf<<<(T_ + 255) / 256, 256, 0, stream>>>(Cf, b_out, lnf_w, lnf_b,
                                                (float*)d_out);
}